// Round 6
// baseline (1614.803 us; speedup 1.0000x reference)
//
#include <hip/hip_runtime.h>
#include <math.h>

constexpr int INF_ = 128;  // IN
constexpr int H_   = 4;
constexpr int C_   = 32;
constexpr int R_   = 8;
constexpr int NB_  = 4;    // nodes per block in node_fused
constexpr int QS_  = 36;   // padded row stride for q/k/v in LDS
constexpr int NS_  = R_ * QS_;   // 288 floats per node

// -------------------------------------------------------------------------
// CSR build at 4-node GROUP granularity.
// -------------------------------------------------------------------------
__global__ __launch_bounds__(256) void count_edges(
    const int* __restrict__ ei, int* __restrict__ counts, int E)
{
    int e = blockIdx.x * 256 + threadIdx.x;
    if (e >= E) return;
    int dst = ei[E + e];
    atomicAdd(&counts[dst >> 2], 1);
}

// single-block exclusive scan of counts[0..G) -> offsets[0..G]
__global__ __launch_bounds__(1024) void scan_offsets(
    const int* __restrict__ counts, int* __restrict__ offsets, int G)
{
    __shared__ int wsum[16];
    __shared__ int chunk_tot;
    const int tid  = threadIdx.x;
    const int lane = tid & 63;
    const int wid  = tid >> 6;
    int carry = 0;
    for (int base = 0; base < G; base += 1024) {
        int i = base + tid;
        int v = (i < G) ? counts[i] : 0;
        int s = v;
        #pragma unroll
        for (int d = 1; d < 64; d <<= 1) {
            int t = __shfl_up(s, d, 64);
            if (lane >= d) s += t;
        }
        if (lane == 63) wsum[wid] = s;
        __syncthreads();
        if (tid == 0) {
            int acc = 0;
            #pragma unroll
            for (int w = 0; w < 16; ++w) { int t = wsum[w]; wsum[w] = acc; acc += t; }
            chunk_tot = acc;
        }
        __syncthreads();
        int excl = carry + wsum[wid] + (s - v);
        if (i < G) offsets[i] = excl;
        carry += chunk_tot;
        __syncthreads();
    }
    if (tid == 0) offsets[G] = carry;
}

// scatter edges into group-sorted order, packed: src | r<<17 | (dst&3)<<20
__global__ __launch_bounds__(256) void scatter_edges(
    const int* __restrict__ ei, const int* __restrict__ et,
    int* __restrict__ cursor, int* __restrict__ sorted, int E)
{
    int e = blockIdx.x * 256 + threadIdx.x;
    if (e >= E) return;
    int src = ei[e];
    int dst = ei[E + e];
    int r   = et[e];
    int pos = atomicAdd(&cursor[dst >> 2], 1);
    sorted[pos] = src | (r << 17) | ((dst & 3) << 20);
}

// -------------------------------------------------------------------------
// M_i[d][r*4+h] = sum_c Wi[d][h*32+c] * natt[r*4+h][c]
// M_j[d][r*4+h] = sum_c Wj[d][h*32+c] * natt[r*4+h][32+c]
// -------------------------------------------------------------------------
__global__ __launch_bounds__(256) void prep_M(
    const float* __restrict__ Wi, const float* __restrict__ Wj,
    const float* __restrict__ natt,
    float* __restrict__ M_i, float* __restrict__ M_j)
{
    int idx = blockIdx.x * 256 + threadIdx.x;   // 0..8191
    int which = idx >> 12;         // 0: M_i, 1: M_j
    int d  = (idx >> 5) & 127;
    int rh = idx & 31;
    int h  = rh & 3;
    const float* W   = which ? Wj : Wi;
    const float* att = natt + rh * 64 + (which ? 32 : 0);
    float acc = 0.f;
    #pragma unroll
    for (int c = 0; c < 32; ++c)
        acc += W[d * 128 + h * 32 + c] * att[c];
    (which ? M_j : M_i)[d * 32 + rh] = acc;
}

// -------------------------------------------------------------------------
// Fused node GEMMs: 352 output cols per node.
// -------------------------------------------------------------------------
__global__ __launch_bounds__(256) void fused_gemm(
    const float* __restrict__ x,
    const float* __restrict__ Wj,
    const float* __restrict__ Wsn,
    const float* __restrict__ Wself,
    const float* __restrict__ M_i,
    const float* __restrict__ M_j,
    float* __restrict__ h_j,
    float* __restrict__ self_node,
    float* __restrict__ self_term,   // = d_out
    float* __restrict__ AI,
    float* __restrict__ AJ,
    int N)
{
    __shared__ float xs[32][128];
    const int n0  = blockIdx.x * 32;
    const int tid = threadIdx.x;

    #pragma unroll
    for (int j = 0; j < 4; ++j) {
        int f4   = tid + 256 * j;
        int row  = f4 >> 5;
        int col4 = f4 & 31;
        float4 v = make_float4(0.f, 0.f, 0.f, 0.f);
        if (n0 + row < N)
            v = *(const float4*)(x + (size_t)(n0 + row) * 128 + col4 * 4);
        *(float4*)(&xs[row][col4 * 4]) = v;
    }
    __syncthreads();

    const int c_local = tid & 31;
    const int n_base  = tid >> 5;
    const int col     = blockIdx.y * 32 + c_local;

    const float* W; float* outb; int wcol, wstride, ostride;
    if (col < 128)      { W = Wj;    outb = h_j;       wcol = col;       wstride = 128; ostride = 128; }
    else if (col < 256) { W = Wsn;   outb = self_node; wcol = col - 128; wstride = 128; ostride = 128; }
    else if (col < 288) { W = Wself; outb = self_term; wcol = col - 256; wstride = 32;  ostride = 32;  }
    else if (col < 320) { W = M_i;   outb = AI;        wcol = col - 288; wstride = 32;  ostride = 32;  }
    else                { W = M_j;   outb = AJ;        wcol = col - 320; wstride = 32;  ostride = 32;  }

    float acc0 = 0.f, acc1 = 0.f, acc2 = 0.f, acc3 = 0.f;
    #pragma unroll 8
    for (int k = 0; k < 128; ++k) {
        float w = W[k * wstride + wcol];
        acc0 += xs[n_base     ][k] * w;
        acc1 += xs[n_base +  8][k] * w;
        acc2 += xs[n_base + 16][k] * w;
        acc3 += xs[n_base + 24][k] * w;
    }
    if (n0 + n_base      < N) outb[(size_t)(n0 + n_base     ) * ostride + wcol] = acc0;
    if (n0 + n_base +  8 < N) outb[(size_t)(n0 + n_base +  8) * ostride + wcol] = acc1;
    if (n0 + n_base + 16 < N) outb[(size_t)(n0 + n_base + 16) * ostride + wcol] = acc2;
    if (n0 + n_base + 24 < N) outb[(size_t)(n0 + n_base + 24) * ostride + wcol] = acc3;
}

// -------------------------------------------------------------------------
// Fused per-node aggregation + relation attention tail.
// 256 threads / 4 nodes per block; LDS ~18.6 KB -> 8 blocks/CU = 32 waves/CU.
// -------------------------------------------------------------------------
__global__ __launch_bounds__(256, 8) void node_fused(
    const float* __restrict__ h_j,
    const float* __restrict__ self_node,
    const float* __restrict__ AJ,        // [N,32]
    const float* __restrict__ AI,        // [N,32]
    const int*   __restrict__ offsets,   // [G+1]
    const int*   __restrict__ sorted,    // [E]
    const float* __restrict__ W_q,       // [R,128,32]
    const float* __restrict__ W_k,
    const float* __restrict__ W_v,
    const float* __restrict__ W_rel,     // [R]
    float* __restrict__ out,             // [N,32]; holds self_term on entry
    int N)
{
    __shared__ float agg[NB_][R_][128];   // 16 KB; overlaid with padded q/k/v later
    __shared__ float den[NB_][R_][H_];    // 512 B
    __shared__ float ai [NB_][32];        // 512 B
    __shared__ float psi_l[NB_ * 64];     // 1 KB [n][rr][ss]
    __shared__ float mskl[NB_ * 8];       // 128 B

    const int tid = threadIdx.x;
    const int n0  = blockIdx.x * NB_;
    float* aggp = &agg[0][0][0];

    // zero accumulators (float4), load AI tile
    for (int i4 = tid; i4 < NB_ * R_ * 32; i4 += 256)
        ((float4*)aggp)[i4] = make_float4(0.f, 0.f, 0.f, 0.f);
    if (tid < NB_ * R_ * H_) (&den[0][0][0])[tid] = 0.f;      // 128
    if (tid < NB_ * 32) {
        int nl = tid >> 5, rh = tid & 31;
        ai[nl][rh] = (n0 + nl < N) ? AI[(size_t)(n0 + nl) * 32 + rh] : 0.f;
    }
    __syncthreads();

    // ---- edge aggregation: 8 edges in flight (one per half-wave) ----
    {
        const int e0   = offsets[blockIdx.x];
        const int e1   = offsets[blockIdx.x + 1];
        const int slot = tid >> 5;        // 0..7
        const int l    = tid & 31;

        for (int k = e0 + slot; k < e1; k += 8) {
            int pk  = sorted[k];
            int src = pk & 0x1FFFF;
            int r   = (pk >> 17) & 7;
            int nl  = (pk >> 20) & 3;
            const float* hjp = h_j + (size_t)src * 128 + l;
            float v0 = hjp[0], v1 = hjp[32], v2 = hjp[64], v3 = hjp[96];
            float4 ajv = *(const float4*)(AJ + (size_t)src * 32 + r * 4);
            const float* aip = &ai[nl][r * 4];
            float a0 = aip[0] + ajv.x; a0 = (a0 > 0.f) ? a0 : 0.2f * a0;
            float a1 = aip[1] + ajv.y; a1 = (a1 > 0.f) ? a1 : 0.2f * a1;
            float a2 = aip[2] + ajv.z; a2 = (a2 > 0.f) ? a2 : 0.2f * a2;
            float a3 = aip[3] + ajv.w; a3 = (a3 > 0.f) ? a3 : 0.2f * a3;
            float x0 = __expf(a0), x1 = __expf(a1), x2 = __expf(a2), x3 = __expf(a3);
            if (l < 4) {
                float myex = (l == 0) ? x0 : (l == 1) ? x1 : (l == 2) ? x2 : x3;
                atomicAdd(&den[nl][r][l], myex);
            }
            float* dp = &agg[nl][r][l];
            atomicAdd(dp,      x0 * v0);
            atomicAdd(dp + 32, x1 * v1);
            atomicAdd(dp + 64, x2 * v2);
            atomicAdd(dp + 96, x3 * v3);
        }
    }
    __syncthreads();

    // ---- z = agg/(den+eps) + self_node  (float4) ----
    for (int i4 = tid; i4 < NB_ * R_ * 32; i4 += 256) {
        int nl  = i4 >> 8;
        int rr  = (i4 >> 5) & 7;
        int hc4 = i4 & 31;
        int h   = hc4 >> 3;
        float invd = 1.f / (den[nl][rr][h] + 1e-16f);
        float4 a4 = ((float4*)aggp)[i4];
        a4.x *= invd; a4.y *= invd; a4.z *= invd; a4.w *= invd;
        if (n0 + nl < N) {
            float4 s4 = *(const float4*)(self_node + (size_t)(n0 + nl) * 128 + hc4 * 4);
            a4.x += s4.x; a4.y += s4.y; a4.z += s4.z; a4.w += s4.w;
        }
        ((float4*)aggp)[i4] = a4;
    }
    __syncthreads();

    // ---- q,k,v: wave w handles relations {w, w+4}; halves handle 2 nodes each ----
    const int w    = tid >> 6;          // 0..3
    const int lane = tid & 63;
    const int c    = lane & 31;
    const int nh   = lane >> 5;         // 0: nodes 0,1  1: nodes 2,3
    const int r0   = w, r1 = w + 4;
    const int na   = nh * 2, nb2 = nh * 2 + 1;

    float q00 = 0.f, q01 = 0.f, q10 = 0.f, q11 = 0.f;
    float k00 = 0.f, k01 = 0.f, k10 = 0.f, k11 = 0.f;
    float v00 = 0.f, v01 = 0.f, v10 = 0.f, v11 = 0.f;
    {
        const float* wq0p = W_q + r0 * 4096 + c;
        const float* wk0p = W_k + r0 * 4096 + c;
        const float* wv0p = W_v + r0 * 4096 + c;
        const float* wq1p = W_q + r1 * 4096 + c;
        const float* wk1p = W_k + r1 * 4096 + c;
        const float* wv1p = W_v + r1 * 4096 + c;
        for (int d = 0; d < 128; d += 4) {
            float4 za0 = *(const float4*)&agg[na ][r0][d];
            float4 zb0 = *(const float4*)&agg[nb2][r0][d];
            float4 za1 = *(const float4*)&agg[na ][r1][d];
            float4 zb1 = *(const float4*)&agg[nb2][r1][d];
            #pragma unroll
            for (int j = 0; j < 4; ++j) {
                float wq0 = wq0p[(d + j) * 32], wk0 = wk0p[(d + j) * 32], wv0 = wv0p[(d + j) * 32];
                float wq1 = wq1p[(d + j) * 32], wk1 = wk1p[(d + j) * 32], wv1 = wv1p[(d + j) * 32];
                float za0j = (&za0.x)[j], zb0j = (&zb0.x)[j];
                float za1j = (&za1.x)[j], zb1j = (&zb1.x)[j];
                q00 += za0j * wq0; k00 += za0j * wk0; v00 += za0j * wv0;
                q01 += zb0j * wq0; k01 += zb0j * wk0; v01 += zb0j * wv0;
                q10 += za1j * wq1; k10 += za1j * wk1; v10 += za1j * wv1;
                q11 += zb1j * wq1; k11 += zb1j * wk1; v11 += zb1j * wv1;
            }
        }
    }
    __syncthreads();   // all z reads done; overlay padded q/k/v onto agg region
    float* qs  = aggp;                      // [n][r][QS_], NB*NS_ = 1152 floats
    float* ks2 = aggp + NB_ * NS_;
    float* vs2 = aggp + 2 * NB_ * NS_;      // total 3456 <= 4096
    qs [na  * NS_ + r0 * QS_ + c] = q00;
    qs [nb2 * NS_ + r0 * QS_ + c] = q01;
    qs [na  * NS_ + r1 * QS_ + c] = q10;
    qs [nb2 * NS_ + r1 * QS_ + c] = q11;
    ks2[na  * NS_ + r0 * QS_ + c] = k00;
    ks2[nb2 * NS_ + r0 * QS_ + c] = k01;
    ks2[na  * NS_ + r1 * QS_ + c] = k10;
    ks2[nb2 * NS_ + r1 * QS_ + c] = k11;
    vs2[na  * NS_ + r0 * QS_ + c] = v00;
    vs2[nb2 * NS_ + r0 * QS_ + c] = v01;
    vs2[na  * NS_ + r1 * QS_ + c] = v10;
    vs2[nb2 * NS_ + r1 * QS_ + c] = v11;
    __syncthreads();

    // ---- psi[n][rr][ss] = <q[n,rr], k[n,ss]> (1 dot per thread) ----
    {
        int n = tid >> 6, rr = (tid >> 3) & 7, ss = tid & 7;
        const float4* q4 = (const float4*)&qs [n * NS_ + rr * QS_];
        const float4* k4 = (const float4*)&ks2[n * NS_ + ss * QS_];
        float p = 0.f;
        #pragma unroll
        for (int c4 = 0; c4 < 8; ++c4) {
            float4 a = q4[c4], b = k4[c4];
            p += a.x * b.x + a.y * b.y + a.z * b.z + a.w * b.w;
        }
        psi_l[tid] = p;
    }
    __syncthreads();
    // softmax over ss
    if (tid < NB_ * 8) {
        float* row = &psi_l[tid * 8];
        float m = -INFINITY;
        #pragma unroll
        for (int s = 0; s < 8; ++s) m = fmaxf(m, row[s]);
        float sum = 0.f;
        #pragma unroll
        for (int s = 0; s < 8; ++s) { float e = __expf(row[s] - m); row[s] = e; sum += e; }
        float inv = 1.f / sum;
        #pragma unroll
        for (int s = 0; s < 8; ++s) row[s] *= inv;
    }
    __syncthreads();

    // ---- delta[n][r][c] = sum_s psi * v (4 (n,r) pairs per lane) ----
    float d00 = 0.f, d01 = 0.f, d10 = 0.f, d11 = 0.f;
    #pragma unroll
    for (int s = 0; s < 8; ++s) {
        float va0 = vs2[na  * NS_ + s * QS_ + c];
        float vb0 = vs2[nb2 * NS_ + s * QS_ + c];
        d00 += psi_l[na  * 64 + r0 * 8 + s] * va0;
        d01 += psi_l[nb2 * 64 + r0 * 8 + s] * vb0;
        d10 += psi_l[na  * 64 + r1 * 8 + s] * va0;
        d11 += psi_l[nb2 * 64 + r1 * 8 + s] * vb0;
    }
    __syncthreads();
    qs[na  * NS_ + r0 * QS_ + c] = d00;
    qs[nb2 * NS_ + r0 * QS_ + c] = d01;
    qs[na  * NS_ + r1 * QS_ + c] = d10;
    qs[nb2 * NS_ + r1 * QS_ + c] = d11;
    __syncthreads();

    // ---- mask[n][r] = (sum_c delta != 0) ----
    if (tid < NB_ * 8) {
        int n = tid >> 3, rr = tid & 7;
        float s = 0.f;
        #pragma unroll
        for (int cc = 0; cc < 32; ++cc) s += qs[n * NS_ + rr * QS_ + cc];
        mskl[tid] = (s != 0.f) ? 1.f : 0.f;
    }
    __syncthreads();

    // ---- out[n] = sum_r (delta + self_term*mask) * W_rel[r] ----
    if (tid < NB_ * 32) {
        int n = tid >> 5, cc = tid & 31;
        if (n0 + n < N) {
            float st = out[(size_t)(n0 + n) * 32 + cc];   // self_term
            float o = 0.f;
            #pragma unroll
            for (int rr = 0; rr < 8; ++rr)
                o += (qs[n * NS_ + rr * QS_ + cc] + st * mskl[n * 8 + rr]) * W_rel[rr];
            out[(size_t)(n0 + n) * 32 + cc] = o;
        }
    }
}

// -------------------------------------------------------------------------
extern "C" void kernel_launch(void* const* d_in, const int* in_sizes, int n_in,
                              void* d_out, int out_size, void* d_ws, size_t ws_size,
                              hipStream_t stream)
{
    const float* x      = (const float*)d_in[0];
    const int*   ei     = (const int*)  d_in[1];   // [2,E]
    const int*   et     = (const int*)  d_in[2];   // [E]
    const float* Wj     = (const float*)d_in[3];
    const float* Wi     = (const float*)d_in[4];
    const float* natt   = (const float*)d_in[5];
    const float* W_q    = (const float*)d_in[6];
    const float* W_k    = (const float*)d_in[7];
    const float* W_v    = (const float*)d_in[8];
    const float* W_self = (const float*)d_in[9];
    const float* W_sn   = (const float*)d_in[10];
    const float* W_rel  = (const float*)d_in[11];
    float* out = (float*)d_out;

    const int N = in_sizes[0] / INF_;
    const int E = in_sizes[2];
    const int G = (N + NB_ - 1) / NB_;   // 4-node groups

    // workspace layout (~67 MB)
    float* ws        = (float*)d_ws;
    float* h_j       = ws;                               // N*128
    float* self_node = h_j + (size_t)N * 128;            // N*128
    float* AI        = self_node + (size_t)N * 128;      // N*32
    float* AJ        = AI + (size_t)N * 32;              // N*32
    float* M_i       = AJ + (size_t)N * 32;              // 128*32
    float* M_j       = M_i + 128 * 32;                   // 128*32
    int*   counts    = (int*)(M_j + 128 * 32);           // G+1
    int*   offsets   = counts + (G + 1);                 // G+1
    int*   cursor    = offsets + (G + 1);                // G
    int*   sorted    = cursor + G;                       // E

    // ---- CSR build (group granularity) ----
    hipMemsetAsync(counts, 0, (size_t)(G + 1) * sizeof(int), stream);
    count_edges<<<(E + 255) / 256, 256, 0, stream>>>(ei, counts, E);
    scan_offsets<<<1, 1024, 0, stream>>>(counts, offsets, G);
    hipMemcpyAsync(cursor, offsets, (size_t)G * sizeof(int),
                   hipMemcpyDeviceToDevice, stream);
    scatter_edges<<<(E + 255) / 256, 256, 0, stream>>>(ei, et, cursor, sorted, E);

    // ---- node feature GEMMs ----
    prep_M<<<32, 256, 0, stream>>>(Wi, Wj, natt, M_i, M_j);
    dim3 gA((N + 31) / 32, 11);
    fused_gemm<<<gA, 256, 0, stream>>>(x, Wj, W_sn, W_self, M_i, M_j,
                                       h_j, self_node, out, AI, AJ, N);

    // ---- fused aggregation + tail ----
    node_fused<<<G, 256, 0, stream>>>(
        h_j, self_node, AJ, AI, offsets, sorted,
        W_q, W_k, W_v, W_rel, out, N);
}

// Round 7
// 1001.272 us; speedup vs baseline: 1.6128x; 1.6128x over previous
//
#include <hip/hip_runtime.h>
#include <math.h>

constexpr int INF_ = 128;  // IN
constexpr int H_   = 4;
constexpr int C_   = 32;
constexpr int R_   = 8;
constexpr int NB_  = 8;    // nodes per block in node_fused
constexpr int QS_  = 36;   // padded row stride for q/k/v in LDS
constexpr int NS_  = R_ * QS_;   // 288 floats per node
constexpr int EL_  = 256;  // staged edge indices in LDS

__device__ __forceinline__ unsigned short f2bf(float f) {
    unsigned u = __float_as_uint(f);
    u += 0x7FFF + ((u >> 16) & 1);          // round-to-nearest-even
    return (unsigned short)(u >> 16);
}
__device__ __forceinline__ float bf2f(unsigned short b) {
    return __uint_as_float(((unsigned)b) << 16);
}

// -------------------------------------------------------------------------
// CSR build at 8-node GROUP granularity.
// -------------------------------------------------------------------------
__global__ __launch_bounds__(256) void count_edges(
    const int* __restrict__ ei, int* __restrict__ counts, int E)
{
    int e = blockIdx.x * 256 + threadIdx.x;
    if (e >= E) return;
    int dst = ei[E + e];
    atomicAdd(&counts[dst >> 3], 1);
}

__global__ __launch_bounds__(1024) void scan_offsets(
    const int* __restrict__ counts, int* __restrict__ offsets, int G)
{
    __shared__ int wsum[16];
    __shared__ int chunk_tot;
    const int tid  = threadIdx.x;
    const int lane = tid & 63;
    const int wid  = tid >> 6;
    int carry = 0;
    for (int base = 0; base < G; base += 1024) {
        int i = base + tid;
        int v = (i < G) ? counts[i] : 0;
        int s = v;
        #pragma unroll
        for (int d = 1; d < 64; d <<= 1) {
            int t = __shfl_up(s, d, 64);
            if (lane >= d) s += t;
        }
        if (lane == 63) wsum[wid] = s;
        __syncthreads();
        if (tid == 0) {
            int acc = 0;
            #pragma unroll
            for (int w = 0; w < 16; ++w) { int t = wsum[w]; wsum[w] = acc; acc += t; }
            chunk_tot = acc;
        }
        __syncthreads();
        int excl = carry + wsum[wid] + (s - v);
        if (i < G) offsets[i] = excl;
        carry += chunk_tot;
        __syncthreads();
    }
    if (tid == 0) offsets[G] = carry;
}

// packed: src | r<<17 | (dst&7)<<20
__global__ __launch_bounds__(256) void scatter_edges(
    const int* __restrict__ ei, const int* __restrict__ et,
    int* __restrict__ cursor, int* __restrict__ sorted, int E)
{
    int e = blockIdx.x * 256 + threadIdx.x;
    if (e >= E) return;
    int src = ei[e];
    int dst = ei[E + e];
    int r   = et[e];
    int pos = atomicAdd(&cursor[dst >> 3], 1);
    sorted[pos] = src | (r << 17) | ((dst & 7) << 20);
}

// -------------------------------------------------------------------------
// M_i[d][r*4+h] = sum_c Wi[d][h*32+c] * natt[r*4+h][c]
// M_j[d][r*4+h] = sum_c Wj[d][h*32+c] * natt[r*4+h][32+c]
// -------------------------------------------------------------------------
__global__ __launch_bounds__(256) void prep_M(
    const float* __restrict__ Wi, const float* __restrict__ Wj,
    const float* __restrict__ natt,
    float* __restrict__ M_i, float* __restrict__ M_j)
{
    int idx = blockIdx.x * 256 + threadIdx.x;   // 0..8191
    int which = idx >> 12;
    int d  = (idx >> 5) & 127;
    int rh = idx & 31;
    int h  = rh & 3;
    const float* W   = which ? Wj : Wi;
    const float* att = natt + rh * 64 + (which ? 32 : 0);
    float acc = 0.f;
    #pragma unroll
    for (int c = 0; c < 32; ++c)
        acc += W[d * 128 + h * 32 + c] * att[c];
    (which ? M_j : M_i)[d * 32 + rh] = acc;
}

// -------------------------------------------------------------------------
// Fused node GEMMs. h_j emitted as SWIZZLED bf16: hjb[node*128 + (col%32)*4
// + col/32], so edge-phase lane l reads one ushort4 = cols {l,l+32,l+64,l+96}.
// -------------------------------------------------------------------------
__global__ __launch_bounds__(256) void fused_gemm(
    const float* __restrict__ x,
    const float* __restrict__ Wj,
    const float* __restrict__ Wsn,
    const float* __restrict__ Wself,
    const float* __restrict__ M_i,
    const float* __restrict__ M_j,
    unsigned short* __restrict__ hjb,   // [N*128] bf16 swizzled
    float* __restrict__ self_node,
    float* __restrict__ self_term,      // = d_out
    float* __restrict__ AI,
    float* __restrict__ AJ,
    int N)
{
    __shared__ float xs[32][128];
    const int n0  = blockIdx.x * 32;
    const int tid = threadIdx.x;

    #pragma unroll
    for (int j = 0; j < 4; ++j) {
        int f4   = tid + 256 * j;
        int row  = f4 >> 5;
        int col4 = f4 & 31;
        float4 v = make_float4(0.f, 0.f, 0.f, 0.f);
        if (n0 + row < N)
            v = *(const float4*)(x + (size_t)(n0 + row) * 128 + col4 * 4);
        *(float4*)(&xs[row][col4 * 4]) = v;
    }
    __syncthreads();

    const int c_local = tid & 31;
    const int n_base  = tid >> 5;
    const int col     = blockIdx.y * 32 + c_local;   // block-uniform ranges

    const float* W; float* outb = nullptr; int wcol, wstride, ostride;
    bool is_hj = false;
    if (col < 128)      { W = Wj;    is_hj = true;     wcol = col;       wstride = 128; ostride = 128; }
    else if (col < 256) { W = Wsn;   outb = self_node; wcol = col - 128; wstride = 128; ostride = 128; }
    else if (col < 288) { W = Wself; outb = self_term; wcol = col - 256; wstride = 32;  ostride = 32;  }
    else if (col < 320) { W = M_i;   outb = AI;        wcol = col - 288; wstride = 32;  ostride = 32;  }
    else                { W = M_j;   outb = AJ;        wcol = col - 320; wstride = 32;  ostride = 32;  }

    float acc0 = 0.f, acc1 = 0.f, acc2 = 0.f, acc3 = 0.f;
    #pragma unroll 8
    for (int k = 0; k < 128; ++k) {
        float w = W[k * wstride + wcol];
        acc0 += xs[n_base     ][k] * w;
        acc1 += xs[n_base +  8][k] * w;
        acc2 += xs[n_base + 16][k] * w;
        acc3 += xs[n_base + 24][k] * w;
    }
    if (is_hj) {
        int so = c_local * 4 + blockIdx.y;   // swizzled offset within node
        if (n0 + n_base      < N) hjb[(size_t)(n0 + n_base     ) * 128 + so] = f2bf(acc0);
        if (n0 + n_base +  8 < N) hjb[(size_t)(n0 + n_base +  8) * 128 + so] = f2bf(acc1);
        if (n0 + n_base + 16 < N) hjb[(size_t)(n0 + n_base + 16) * 128 + so] = f2bf(acc2);
        if (n0 + n_base + 24 < N) hjb[(size_t)(n0 + n_base + 24) * 128 + so] = f2bf(acc3);
    } else {
        if (n0 + n_base      < N) outb[(size_t)(n0 + n_base     ) * ostride + wcol] = acc0;
        if (n0 + n_base +  8 < N) outb[(size_t)(n0 + n_base +  8) * ostride + wcol] = acc1;
        if (n0 + n_base + 16 < N) outb[(size_t)(n0 + n_base + 16) * ostride + wcol] = acc2;
        if (n0 + n_base + 24 < N) outb[(size_t)(n0 + n_base + 24) * ostride + wcol] = acc3;
    }
}

// -------------------------------------------------------------------------
// Fused per-node aggregation + relation attention tail.
// 256 thr / 8 nodes. Edge phase: LDS-staged indices, batch-4 pipelined
// bf16 gathers (2 lines/edge), conflict-free stride-32 LDS atomics.
// -------------------------------------------------------------------------
__global__ __launch_bounds__(256, 4) void node_fused(
    const unsigned short* __restrict__ hjb,  // [N*128] bf16 swizzled
    const float* __restrict__ self_node,
    const float* __restrict__ AJ,        // [N,32]
    const float* __restrict__ AI,        // [N,32]
    const int*   __restrict__ offsets,   // [G+1]
    const int*   __restrict__ sorted,    // [E]
    const float* __restrict__ W_q,       // [R,128,32]
    const float* __restrict__ W_k,
    const float* __restrict__ W_v,
    const float* __restrict__ W_rel,     // [R]
    float* __restrict__ out,             // [N,32]; holds self_term on entry
    int N)
{
    __shared__ float agg[NB_][R_][128];   // 32 KB; overlaid with padded q/k/v later
    __shared__ float den[NB_][R_][H_];    // 1 KB
    __shared__ float ai [NB_][32];        // 1 KB
    __shared__ float psi_l[NB_ * 64];     // 2 KB
    __shared__ float mskl[NB_ * 8];       // 256 B
    __shared__ int   edges_lds[EL_];      // 1 KB

    const int tid = threadIdx.x;
    const int n0  = blockIdx.x * NB_;
    float* aggp = &agg[0][0][0];

    const int e0 = offsets[blockIdx.x];
    const int e1 = offsets[blockIdx.x + 1];

    // zero accumulators (float4), load AI tile, stage edge indices
    for (int i4 = tid; i4 < NB_ * R_ * 32; i4 += 256)
        ((float4*)aggp)[i4] = make_float4(0.f, 0.f, 0.f, 0.f);
    (&den[0][0][0])[tid] = 0.f;                         // NB*R*H == 256
    {
        int nl = tid >> 5, rh = tid & 31;
        ai[nl][rh] = (n0 + nl < N) ? AI[(size_t)(n0 + nl) * 32 + rh] : 0.f;
    }
    {
        int ecount = e1 - e0; if (ecount > EL_) ecount = EL_;
        if (tid < ecount) edges_lds[tid] = sorted[e0 + tid];
    }
    __syncthreads();

    // ---- edge aggregation: batch-4 pipelined per half-wave ----
    {
        const int slot = tid >> 5;        // 0..7
        const int l    = tid & 31;

        for (int kbase = e0 + slot; kbase < e1; kbase += 32) {
            int     pkv[4];
            ushort4 hv[4];
            float4  aj4[4];
            #pragma unroll
            for (int b = 0; b < 4; ++b) {
                int kk = kbase + b * 8;
                if (kk < e1) {
                    int rel = kk - e0;
                    int pk  = (rel < EL_) ? edges_lds[rel] : sorted[kk];
                    pkv[b] = pk;
                    int src = pk & 0x1FFFF;
                    int r   = (pk >> 17) & 7;
                    hv[b]  = *(const ushort4*)(hjb + (size_t)src * 128 + l * 4);
                    aj4[b] = *(const float4*)(AJ + (size_t)src * 32 + r * 4);
                }
            }
            #pragma unroll
            for (int b = 0; b < 4; ++b) {
                int kk = kbase + b * 8;
                if (kk < e1) {
                    int pk = pkv[b];
                    int r  = (pk >> 17) & 7;
                    int nl = (pk >> 20) & 7;
                    const float* aip = &ai[nl][r * 4];
                    float4 ajv = aj4[b];
                    float a0 = aip[0] + ajv.x; a0 = (a0 > 0.f) ? a0 : 0.2f * a0;
                    float a1 = aip[1] + ajv.y; a1 = (a1 > 0.f) ? a1 : 0.2f * a1;
                    float a2 = aip[2] + ajv.z; a2 = (a2 > 0.f) ? a2 : 0.2f * a2;
                    float a3 = aip[3] + ajv.w; a3 = (a3 > 0.f) ? a3 : 0.2f * a3;
                    float x0 = __expf(a0), x1 = __expf(a1), x2 = __expf(a2), x3 = __expf(a3);
                    if (l < 4) {
                        float myex = (l == 0) ? x0 : (l == 1) ? x1 : (l == 2) ? x2 : x3;
                        atomicAdd(&den[nl][r][l], myex);
                    }
                    float v0 = bf2f(hv[b].x), v1 = bf2f(hv[b].y),
                          v2 = bf2f(hv[b].z), v3 = bf2f(hv[b].w);
                    float* dp = &agg[nl][r][l];
                    atomicAdd(dp,      x0 * v0);
                    atomicAdd(dp + 32, x1 * v1);
                    atomicAdd(dp + 64, x2 * v2);
                    atomicAdd(dp + 96, x3 * v3);
                }
            }
        }
    }
    __syncthreads();

    // ---- z = agg/(den+eps) + self_node  (float4) ----
    for (int i4 = tid; i4 < NB_ * R_ * 32; i4 += 256) {
        int nl  = i4 >> 8;
        int rr  = (i4 >> 5) & 7;
        int hc4 = i4 & 31;
        int h   = hc4 >> 3;
        float invd = 1.f / (den[nl][rr][h] + 1e-16f);
        float4 a4 = ((float4*)aggp)[i4];
        a4.x *= invd; a4.y *= invd; a4.z *= invd; a4.w *= invd;
        if (n0 + nl < N) {
            float4 s4 = *(const float4*)(self_node + (size_t)(n0 + nl) * 128 + hc4 * 4);
            a4.x += s4.x; a4.y += s4.y; a4.z += s4.z; a4.w += s4.w;
        }
        ((float4*)aggp)[i4] = a4;
    }
    __syncthreads();

    // ---- q,k,v: wave w handles relations {w,w+4}; half-waves 4 nodes each ----
    const int w    = tid >> 6;          // 0..3
    const int lane = tid & 63;
    const int c    = lane & 31;
    const int nh   = lane >> 5;         // 0: nodes 0..3, 1: nodes 4..7
    const int r0   = w, r1 = w + 4;
    const int nbase = nh * 4;

    float qa[2][4], ka[2][4], va[2][4];
    #pragma unroll
    for (int s = 0; s < 2; ++s)
        #pragma unroll
        for (int n = 0; n < 4; ++n) { qa[s][n] = 0.f; ka[s][n] = 0.f; va[s][n] = 0.f; }
    {
        const float* wq0 = W_q + r0 * 4096 + c;
        const float* wk0 = W_k + r0 * 4096 + c;
        const float* wv0 = W_v + r0 * 4096 + c;
        const float* wq1 = W_q + r1 * 4096 + c;
        const float* wk1 = W_k + r1 * 4096 + c;
        const float* wv1 = W_v + r1 * 4096 + c;
        for (int d = 0; d < 128; d += 4) {
            float4 z0[4], z1[4];
            #pragma unroll
            for (int n = 0; n < 4; ++n) {
                z0[n] = *(const float4*)&agg[nbase + n][r0][d];
                z1[n] = *(const float4*)&agg[nbase + n][r1][d];
            }
            #pragma unroll
            for (int j = 0; j < 4; ++j) {
                float a0 = wq0[(d + j) * 32], b0 = wk0[(d + j) * 32], c0 = wv0[(d + j) * 32];
                float a1 = wq1[(d + j) * 32], b1 = wk1[(d + j) * 32], c1 = wv1[(d + j) * 32];
                #pragma unroll
                for (int n = 0; n < 4; ++n) {
                    float z0j = (&z0[n].x)[j], z1j = (&z1[n].x)[j];
                    qa[0][n] += z0j * a0; ka[0][n] += z0j * b0; va[0][n] += z0j * c0;
                    qa[1][n] += z1j * a1; ka[1][n] += z1j * b1; va[1][n] += z1j * c1;
                }
            }
        }
    }
    __syncthreads();   // all z reads done; overlay padded q/k/v onto agg region
    float* qs  = aggp;                      // [n][r][QS_], NB*NS_ = 2304 floats
    float* ks2 = aggp + NB_ * NS_;
    float* vs2 = aggp + 2 * NB_ * NS_;      // total 6912 <= 8192
    #pragma unroll
    for (int s = 0; s < 2; ++s) {
        int rr = w + s * 4;
        #pragma unroll
        for (int n = 0; n < 4; ++n) {
            int base = (nbase + n) * NS_ + rr * QS_ + c;
            qs [base] = qa[s][n];
            ks2[base] = ka[s][n];
            vs2[base] = va[s][n];
        }
    }
    __syncthreads();

    // ---- psi[n][rr][ss] = <q[n,rr], k[n,ss]> ----
    for (int idx = tid; idx < NB_ * 64; idx += 256) {
        int n = idx >> 6, rr = (idx >> 3) & 7, ss = idx & 7;
        const float4* q4 = (const float4*)&qs [n * NS_ + rr * QS_];
        const float4* k4 = (const float4*)&ks2[n * NS_ + ss * QS_];
        float p = 0.f;
        #pragma unroll
        for (int c4 = 0; c4 < 8; ++c4) {
            float4 a = q4[c4], b = k4[c4];
            p += a.x * b.x + a.y * b.y + a.z * b.z + a.w * b.w;
        }
        psi_l[idx] = p;
    }
    __syncthreads();
    // softmax over ss
    if (tid < NB_ * 8) {
        float* row = &psi_l[tid * 8];
        float m = -INFINITY;
        #pragma unroll
        for (int s = 0; s < 8; ++s) m = fmaxf(m, row[s]);
        float sum = 0.f;
        #pragma unroll
        for (int s = 0; s < 8; ++s) { float e = __expf(row[s] - m); row[s] = e; sum += e; }
        float inv = 1.f / sum;
        #pragma unroll
        for (int s = 0; s < 8; ++s) row[s] *= inv;
    }
    __syncthreads();

    // ---- delta[n][r][c] = sum_s psi * v ----
    float dl[2][4];
    #pragma unroll
    for (int s = 0; s < 2; ++s)
        #pragma unroll
        for (int n = 0; n < 4; ++n) dl[s][n] = 0.f;
    #pragma unroll
    for (int s = 0; s < 8; ++s) {
        #pragma unroll
        for (int n = 0; n < 4; ++n) {
            float vv = vs2[(nbase + n) * NS_ + s * QS_ + c];
            dl[0][n] += psi_l[(nbase + n) * 64 + r0 * 8 + s] * vv;
            dl[1][n] += psi_l[(nbase + n) * 64 + r1 * 8 + s] * vv;
        }
    }
    __syncthreads();
    #pragma unroll
    for (int s = 0; s < 2; ++s) {
        int rr = w + s * 4;
        #pragma unroll
        for (int n = 0; n < 4; ++n)
            qs[(nbase + n) * NS_ + rr * QS_ + c] = dl[s][n];
    }
    __syncthreads();

    // ---- mask[n][r] = (sum_c delta != 0) ----
    if (tid < NB_ * 8) {
        int n = tid >> 3, rr = tid & 7;
        float s = 0.f;
        #pragma unroll
        for (int cc = 0; cc < 32; ++cc) s += qs[n * NS_ + rr * QS_ + cc];
        mskl[tid] = (s != 0.f) ? 1.f : 0.f;
    }
    __syncthreads();

    // ---- out[n] = sum_r (delta + self_term*mask) * W_rel[r] ----
    {
        int n = tid >> 5, cc = tid & 31;   // 256 = 8 nodes x 32 cols
        if (n0 + n < N) {
            float st = out[(size_t)(n0 + n) * 32 + cc];   // self_term
            float o = 0.f;
            #pragma unroll
            for (int rr = 0; rr < 8; ++rr)
                o += (qs[n * NS_ + rr * QS_ + cc] + st * mskl[n * 8 + rr]) * W_rel[rr];
            out[(size_t)(n0 + n) * 32 + cc] = o;
        }
    }
}

// -------------------------------------------------------------------------
extern "C" void kernel_launch(void* const* d_in, const int* in_sizes, int n_in,
                              void* d_out, int out_size, void* d_ws, size_t ws_size,
                              hipStream_t stream)
{
    const float* x      = (const float*)d_in[0];
    const int*   ei     = (const int*)  d_in[1];   // [2,E]
    const int*   et     = (const int*)  d_in[2];   // [E]
    const float* Wj     = (const float*)d_in[3];
    const float* Wi     = (const float*)d_in[4];
    const float* natt   = (const float*)d_in[5];
    const float* W_q    = (const float*)d_in[6];
    const float* W_k    = (const float*)d_in[7];
    const float* W_v    = (const float*)d_in[8];
    const float* W_self = (const float*)d_in[9];
    const float* W_sn   = (const float*)d_in[10];
    const float* W_rel  = (const float*)d_in[11];
    float* out = (float*)d_out;

    const int N = in_sizes[0] / INF_;
    const int E = in_sizes[2];
    const int G = (N + NB_ - 1) / NB_;   // 8-node groups

    // workspace layout (~54 MB)
    float* ws        = (float*)d_ws;
    float* self_node = ws;                               // N*128
    float* AI        = self_node + (size_t)N * 128;      // N*32
    float* AJ        = AI + (size_t)N * 32;              // N*32
    float* M_i       = AJ + (size_t)N * 32;              // 128*32
    float* M_j       = M_i + 128 * 32;                   // 128*32
    unsigned short* hjb = (unsigned short*)(M_j + 128 * 32);  // N*128 bf16
    int*   counts    = (int*)(hjb + (size_t)N * 128);    // G+1
    int*   offsets   = counts + (G + 1);                 // G+1
    int*   cursor    = offsets + (G + 1);                // G
    int*   sorted    = cursor + G;                       // E

    // ---- CSR build (group granularity) ----
    hipMemsetAsync(counts, 0, (size_t)(G + 1) * sizeof(int), stream);
    count_edges<<<(E + 255) / 256, 256, 0, stream>>>(ei, counts, E);
    scan_offsets<<<1, 1024, 0, stream>>>(counts, offsets, G);
    hipMemcpyAsync(cursor, offsets, (size_t)G * sizeof(int),
                   hipMemcpyDeviceToDevice, stream);
    scatter_edges<<<(E + 255) / 256, 256, 0, stream>>>(ei, et, cursor, sorted, E);

    // ---- node feature GEMMs ----
    prep_M<<<32, 256, 0, stream>>>(Wi, Wj, natt, M_i, M_j);
    dim3 gA((N + 31) / 32, 11);
    fused_gemm<<<gA, 256, 0, stream>>>(x, Wj, W_sn, W_self, M_i, M_j,
                                       hjb, self_node, out, AI, AJ, N);

    // ---- fused aggregation + tail ----
    node_fused<<<G, 256, 0, stream>>>(
        hjb, self_node, AJ, AI, offsets, sorted,
        W_q, W_k, W_v, W_rel, out, N);
}

// Round 8
// 882.601 us; speedup vs baseline: 1.8296x; 1.1345x over previous
//
#include <hip/hip_runtime.h>
#include <hip/hip_fp16.h>
#include <math.h>

constexpr int INF_ = 128;  // IN
constexpr int H_   = 4;
constexpr int C_   = 32;
constexpr int R_   = 8;
constexpr int NB_  = 8;    // nodes per block
constexpr int QS_  = 36;   // padded row stride for q/k/v in LDS
constexpr int NS_  = R_ * QS_;   // 288 floats per node
constexpr int EMAX_ = 320; // staged edges per block (mean 102, sigma ~10)

__device__ __forceinline__ unsigned short f2h(float f) {
    return __half_as_ushort(__float2half(f));
}
__device__ __forceinline__ float h2f(unsigned short u) {
    return __half2float(__ushort_as_half(u));
}

// -------------------------------------------------------------------------
// CSR build at 8-node GROUP granularity (unchanged, proven).
// -------------------------------------------------------------------------
__global__ __launch_bounds__(256) void count_edges(
    const int* __restrict__ ei, int* __restrict__ counts, int E)
{
    int e = blockIdx.x * 256 + threadIdx.x;
    if (e >= E) return;
    int dst = ei[E + e];
    atomicAdd(&counts[dst >> 3], 1);
}

__global__ __launch_bounds__(1024) void scan_offsets(
    const int* __restrict__ counts, int* __restrict__ offsets, int G)
{
    __shared__ int wsum[16];
    __shared__ int chunk_tot;
    const int tid  = threadIdx.x;
    const int lane = tid & 63;
    const int wid  = tid >> 6;
    int carry = 0;
    for (int base = 0; base < G; base += 1024) {
        int i = base + tid;
        int v = (i < G) ? counts[i] : 0;
        int s = v;
        #pragma unroll
        for (int d = 1; d < 64; d <<= 1) {
            int t = __shfl_up(s, d, 64);
            if (lane >= d) s += t;
        }
        if (lane == 63) wsum[wid] = s;
        __syncthreads();
        if (tid == 0) {
            int acc = 0;
            #pragma unroll
            for (int w = 0; w < 16; ++w) { int t = wsum[w]; wsum[w] = acc; acc += t; }
            chunk_tot = acc;
        }
        __syncthreads();
        int excl = carry + wsum[wid] + (s - v);
        if (i < G) offsets[i] = excl;
        carry += chunk_tot;
        __syncthreads();
    }
    if (tid == 0) offsets[G] = carry;
}

// packed: src | r<<17 | (dst&7)<<20
__global__ __launch_bounds__(256) void scatter_edges(
    const int* __restrict__ ei, const int* __restrict__ et,
    int* __restrict__ cursor, int* __restrict__ sorted, int E)
{
    int e = blockIdx.x * 256 + threadIdx.x;
    if (e >= E) return;
    int src = ei[e];
    int dst = ei[E + e];
    int r   = et[e];
    int pos = atomicAdd(&cursor[dst >> 3], 1);
    sorted[pos] = src | (r << 17) | ((dst & 7) << 20);
}

// -------------------------------------------------------------------------
// M_i[d][r*4+h] = sum_c Wi[d][h*32+c] * natt[r*4+h][c]
// M_j[d][r*4+h] = sum_c Wj[d][h*32+c] * natt[r*4+h][32+c]
// -------------------------------------------------------------------------
__global__ __launch_bounds__(256) void prep_M(
    const float* __restrict__ Wi, const float* __restrict__ Wj,
    const float* __restrict__ natt,
    float* __restrict__ M_i, float* __restrict__ M_j)
{
    int idx = blockIdx.x * 256 + threadIdx.x;   // 0..8191
    int which = idx >> 12;
    int d  = (idx >> 5) & 127;
    int rh = idx & 31;
    int h  = rh & 3;
    const float* W   = which ? Wj : Wi;
    const float* att = natt + rh * 64 + (which ? 32 : 0);
    float acc = 0.f;
    #pragma unroll
    for (int c = 0; c < 32; ++c)
        acc += W[d * 128 + h * 32 + c] * att[c];
    (which ? M_j : M_i)[d * 32 + rh] = acc;
}

// -------------------------------------------------------------------------
// Fused node GEMMs. h_j emitted as SWIZZLED fp16: hjb[node*128 + (col%32)*4
// + col/32]; lane l later reads ushort4 = cols {l,l+32,l+64,l+96}.
// -------------------------------------------------------------------------
__global__ __launch_bounds__(256) void fused_gemm(
    const float* __restrict__ x,
    const float* __restrict__ Wj,
    const float* __restrict__ Wsn,
    const float* __restrict__ Wself,
    const float* __restrict__ M_i,
    const float* __restrict__ M_j,
    unsigned short* __restrict__ hjb,   // [N*128] fp16 swizzled
    float* __restrict__ self_node,
    float* __restrict__ self_term,      // = d_out
    float* __restrict__ AI,
    float* __restrict__ AJ,
    int N)
{
    __shared__ float xs[32][128];
    const int n0  = blockIdx.x * 32;
    const int tid = threadIdx.x;

    #pragma unroll
    for (int j = 0; j < 4; ++j) {
        int f4   = tid + 256 * j;
        int row  = f4 >> 5;
        int col4 = f4 & 31;
        float4 v = make_float4(0.f, 0.f, 0.f, 0.f);
        if (n0 + row < N)
            v = *(const float4*)(x + (size_t)(n0 + row) * 128 + col4 * 4);
        *(float4*)(&xs[row][col4 * 4]) = v;
    }
    __syncthreads();

    const int c_local = tid & 31;
    const int n_base  = tid >> 5;
    const int col     = blockIdx.y * 32 + c_local;   // block-uniform ranges

    const float* W; float* outb = nullptr; int wcol, wstride, ostride;
    bool is_hj = false;
    if (col < 128)      { W = Wj;    is_hj = true;     wcol = col;       wstride = 128; ostride = 128; }
    else if (col < 256) { W = Wsn;   outb = self_node; wcol = col - 128; wstride = 128; ostride = 128; }
    else if (col < 288) { W = Wself; outb = self_term; wcol = col - 256; wstride = 32;  ostride = 32;  }
    else if (col < 320) { W = M_i;   outb = AI;        wcol = col - 288; wstride = 32;  ostride = 32;  }
    else                { W = M_j;   outb = AJ;        wcol = col - 320; wstride = 32;  ostride = 32;  }

    float acc0 = 0.f, acc1 = 0.f, acc2 = 0.f, acc3 = 0.f;
    #pragma unroll 8
    for (int k = 0; k < 128; ++k) {
        float w = W[k * wstride + wcol];
        acc0 += xs[n_base     ][k] * w;
        acc1 += xs[n_base +  8][k] * w;
        acc2 += xs[n_base + 16][k] * w;
        acc3 += xs[n_base + 24][k] * w;
    }
    if (is_hj) {
        int so = c_local * 4 + blockIdx.y;   // swizzled offset within node
        if (n0 + n_base      < N) hjb[(size_t)(n0 + n_base     ) * 128 + so] = f2h(acc0);
        if (n0 + n_base +  8 < N) hjb[(size_t)(n0 + n_base +  8) * 128 + so] = f2h(acc1);
        if (n0 + n_base + 16 < N) hjb[(size_t)(n0 + n_base + 16) * 128 + so] = f2h(acc2);
        if (n0 + n_base + 24 < N) hjb[(size_t)(n0 + n_base + 24) * 128 + so] = f2h(acc3);
    } else {
        if (n0 + n_base      < N) outb[(size_t)(n0 + n_base     ) * ostride + wcol] = acc0;
        if (n0 + n_base +  8 < N) outb[(size_t)(n0 + n_base +  8) * ostride + wcol] = acc1;
        if (n0 + n_base + 16 < N) outb[(size_t)(n0 + n_base + 16) * ostride + wcol] = acc2;
        if (n0 + n_base + 24 < N) outb[(size_t)(n0 + n_base + 24) * ostride + wcol] = acc3;
    }
}

// -------------------------------------------------------------------------
// PHASE 1: edge aggregation -> z (fp16, global).
// 256 thr / 8 nodes. Edges counting-sorted in LDS by (node, r); each
// half-wave owns one node and accumulates each (n,r) run in REGISTERS,
// flushing once per run (atomicAdd; ~26 lane-RMW/node vs 128/edge before).
// -------------------------------------------------------------------------
__global__ __launch_bounds__(256) void edge_z(
    const unsigned short* __restrict__ hjb,  // [N*128] fp16 swizzled
    const float* __restrict__ self_node,
    const float* __restrict__ AJ,        // [N,32]
    const float* __restrict__ AI,        // [N,32]
    const int*   __restrict__ offsets,   // [G+1]
    const int*   __restrict__ sorted,    // [E]
    unsigned short* __restrict__ zg,     // [N*1024] fp16: z[n][r][d]
    int N)
{
    __shared__ float agg[NB_][R_][128];   // 32 KB
    __shared__ float den[NB_][R_][H_];    // 1 KB
    __shared__ float ai [NB_][32];        // 1 KB
    __shared__ int   ebuf[EMAX_];         // 1.25 KB
    __shared__ int   sbuf[EMAX_];         // 1.25 KB
    __shared__ int   bstart[64];
    __shared__ int   bcur[64];

    const int tid = threadIdx.x;
    const int n0  = blockIdx.x * NB_;
    float* aggp = &agg[0][0][0];

    const int e0 = offsets[blockIdx.x];
    const int e1 = offsets[blockIdx.x + 1];
    const int ecount_raw = e1 - e0;
    const int ecount = (ecount_raw < EMAX_) ? ecount_raw : EMAX_;

    // init
    for (int i4 = tid; i4 < NB_ * R_ * 32; i4 += 256)
        ((float4*)aggp)[i4] = make_float4(0.f, 0.f, 0.f, 0.f);
    (&den[0][0][0])[tid] = 0.f;                     // NB*R*H == 256
    {
        int nl = tid >> 5, rh = tid & 31;
        ai[nl][rh] = (n0 + nl < N) ? AI[(size_t)(n0 + nl) * 32 + rh] : 0.f;
    }
    if (tid < 64) bstart[tid] = 0;
    for (int i = tid; i < ecount; i += 256) ebuf[i] = sorted[e0 + i];
    __syncthreads();

    // bucket counts (key = nl*8 + r)
    for (int i = tid; i < ecount; i += 256) {
        int pk = ebuf[i];
        int key = (((pk >> 20) & 7) << 3) | ((pk >> 17) & 7);
        atomicAdd(&bstart[key], 1);
    }
    __syncthreads();
    // exclusive scan of 64 bucket counts (wave 0)
    if (tid < 64) {
        int v = bstart[tid];
        int s = v;
        #pragma unroll
        for (int d = 1; d < 64; d <<= 1) {
            int t = __shfl_up(s, d, 64);
            if (tid >= d) s += t;
        }
        bstart[tid] = s - v;
        bcur[tid]   = s - v;
    }
    __syncthreads();
    // scatter into sorted order
    for (int i = tid; i < ecount; i += 256) {
        int pk = ebuf[i];
        int key = (((pk >> 20) & 7) << 3) | ((pk >> 17) & 7);
        int pos = atomicAdd(&bcur[key], 1);
        sbuf[pos] = pk;
    }
    __syncthreads();

    // ---- register-accumulated walk: half-wave = one node ----
    {
        const int nl = tid >> 5;          // 0..7
        const int l  = tid & 31;
        int s_ = bstart[nl * 8];
        int t_ = (nl == 7) ? ecount : bstart[nl * 8 + 8];

        int cur_r = -1;
        float acc0 = 0.f, acc1 = 0.f, acc2 = 0.f, acc3 = 0.f;
        float dn0 = 0.f, dn1 = 0.f, dn2 = 0.f, dn3 = 0.f;

        int pk = 0, src = 0, r = 0;
        ushort4 hv = make_ushort4(0,0,0,0);
        float4  aj = make_float4(0.f,0.f,0.f,0.f);
        if (s_ < t_) {
            pk = sbuf[s_]; src = pk & 0x1FFFF; r = (pk >> 17) & 7;
            hv = *(const ushort4*)(hjb + (size_t)src * 128 + l * 4);
            aj = *(const float4*)(AJ + (size_t)src * 32 + r * 4);
        }
        for (int e = s_; e < t_; ++e) {
            int pk2 = 0, src2 = 0, r2 = 0;
            ushort4 hv2 = hv; float4 aj2 = aj;
            if (e + 1 < t_) {
                pk2 = sbuf[e + 1]; src2 = pk2 & 0x1FFFF; r2 = (pk2 >> 17) & 7;
                hv2 = *(const ushort4*)(hjb + (size_t)src2 * 128 + l * 4);
                aj2 = *(const float4*)(AJ + (size_t)src2 * 32 + r2 * 4);
            }
            if (r != cur_r) {
                if (cur_r >= 0) {
                    float* dp = &agg[nl][cur_r][l];
                    atomicAdd(dp,      acc0); atomicAdd(dp + 32, acc1);
                    atomicAdd(dp + 64, acc2); atomicAdd(dp + 96, acc3);
                    if (l < 4) {
                        float dv = (l == 0) ? dn0 : (l == 1) ? dn1 : (l == 2) ? dn2 : dn3;
                        atomicAdd(&den[nl][cur_r][l], dv);
                    }
                }
                cur_r = r;
                acc0 = acc1 = acc2 = acc3 = 0.f;
                dn0 = dn1 = dn2 = dn3 = 0.f;
            }
            const float* aip = &ai[nl][r * 4];
            float a0 = aip[0] + aj.x; a0 = (a0 > 0.f) ? a0 : 0.2f * a0;
            float a1 = aip[1] + aj.y; a1 = (a1 > 0.f) ? a1 : 0.2f * a1;
            float a2 = aip[2] + aj.z; a2 = (a2 > 0.f) ? a2 : 0.2f * a2;
            float a3 = aip[3] + aj.w; a3 = (a3 > 0.f) ? a3 : 0.2f * a3;
            float x0 = __expf(a0), x1 = __expf(a1), x2 = __expf(a2), x3 = __expf(a3);
            dn0 += x0; dn1 += x1; dn2 += x2; dn3 += x3;
            acc0 += x0 * h2f(hv.x); acc1 += x1 * h2f(hv.y);
            acc2 += x2 * h2f(hv.z); acc3 += x3 * h2f(hv.w);
            pk = pk2; src = src2; r = r2; hv = hv2; aj = aj2;
        }
        if (cur_r >= 0) {
            float* dp = &agg[nl][cur_r][l];
            atomicAdd(dp,      acc0); atomicAdd(dp + 32, acc1);
            atomicAdd(dp + 64, acc2); atomicAdd(dp + 96, acc3);
            if (l < 4) {
                float dv = (l == 0) ? dn0 : (l == 1) ? dn1 : (l == 2) ? dn2 : dn3;
                atomicAdd(&den[nl][cur_r][l], dv);
            }
        }
    }
    // overflow fallback (practically never taken: mean 102 edges, cap 320)
    if (ecount_raw > EMAX_) {
        const int slot = tid >> 5;
        const int l    = tid & 31;
        for (int k = e0 + EMAX_ + slot; k < e1; k += 8) {
            int pk  = sorted[k];
            int src = pk & 0x1FFFF;
            int r   = (pk >> 17) & 7;
            int nl  = (pk >> 20) & 7;
            ushort4 hv = *(const ushort4*)(hjb + (size_t)src * 128 + l * 4);
            float4  aj = *(const float4*)(AJ + (size_t)src * 32 + r * 4);
            const float* aip = &ai[nl][r * 4];
            float a0 = aip[0] + aj.x; a0 = (a0 > 0.f) ? a0 : 0.2f * a0;
            float a1 = aip[1] + aj.y; a1 = (a1 > 0.f) ? a1 : 0.2f * a1;
            float a2 = aip[2] + aj.z; a2 = (a2 > 0.f) ? a2 : 0.2f * a2;
            float a3 = aip[3] + aj.w; a3 = (a3 > 0.f) ? a3 : 0.2f * a3;
            float x0 = __expf(a0), x1 = __expf(a1), x2 = __expf(a2), x3 = __expf(a3);
            if (l < 4) {
                float myex = (l == 0) ? x0 : (l == 1) ? x1 : (l == 2) ? x2 : x3;
                atomicAdd(&den[nl][r][l], myex);
            }
            float* dp = &agg[nl][r][l];
            atomicAdd(dp,      x0 * h2f(hv.x));
            atomicAdd(dp + 32, x1 * h2f(hv.y));
            atomicAdd(dp + 64, x2 * h2f(hv.z));
            atomicAdd(dp + 96, x3 * h2f(hv.w));
        }
    }
    __syncthreads();

    // ---- z = agg/(den+eps) + self_node -> fp16 global ----
    for (int i4 = tid; i4 < NB_ * R_ * 32; i4 += 256) {
        int nl  = i4 >> 8;
        int rr  = (i4 >> 5) & 7;
        int hc4 = i4 & 31;
        int h   = hc4 >> 3;
        float invd = 1.f / (den[nl][rr][h] + 1e-16f);
        float4 a4 = ((float4*)aggp)[i4];
        a4.x *= invd; a4.y *= invd; a4.z *= invd; a4.w *= invd;
        if (n0 + nl < N) {
            float4 s4 = *(const float4*)(self_node + (size_t)(n0 + nl) * 128 + hc4 * 4);
            a4.x += s4.x; a4.y += s4.y; a4.z += s4.z; a4.w += s4.w;
            ushort4 u;
            u.x = f2h(a4.x); u.y = f2h(a4.y); u.z = f2h(a4.z); u.w = f2h(a4.w);
            *(ushort4*)(zg + (size_t)(n0 + nl) * 1024 + rr * 128 + hc4 * 4) = u;
        }
    }
}

// -------------------------------------------------------------------------
// PHASE 2: z -> qkv -> psi softmax -> delta -> out.  256 thr / 8 nodes.
// -------------------------------------------------------------------------
__global__ __launch_bounds__(256) void node_tail(
    const unsigned short* __restrict__ zg,   // [N*1024] fp16
    const float* __restrict__ W_q,       // [R,128,32]
    const float* __restrict__ W_k,
    const float* __restrict__ W_v,
    const float* __restrict__ W_rel,     // [R]
    float* __restrict__ out,             // [N,32]; holds self_term on entry
    int N)
{
    __shared__ float agg[NB_][R_][128];   // 32 KB; overlaid with padded q/k/v
    __shared__ float psi_l[NB_ * 64];     // 2 KB
    __shared__ float mskl[NB_ * 8];       // 256 B

    const int tid = threadIdx.x;
    const int n0  = blockIdx.x * NB_;
    float* aggp = &agg[0][0][0];

    // load z fp16 -> LDS fp32
    for (int i4 = tid; i4 < NB_ * R_ * 32; i4 += 256) {
        int nl = i4 >> 8;
        float4 f;
        if (n0 + nl < N) {
            ushort4 u = *(const ushort4*)(zg + (size_t)(n0 + nl) * 1024 + (i4 & 255) * 4);
            f.x = h2f(u.x); f.y = h2f(u.y); f.z = h2f(u.z); f.w = h2f(u.w);
        } else f = make_float4(0.f, 0.f, 0.f, 0.f);
        ((float4*)aggp)[i4] = f;
    }
    __syncthreads();

    // ---- q,k,v: wave w -> relations {w,w+4}; half-waves 4 nodes each ----
    const int w    = tid >> 6;
    const int lane = tid & 63;
    const int c    = lane & 31;
    const int nh   = lane >> 5;
    const int r0   = w, r1 = w + 4;
    const int nbase = nh * 4;

    float qa[2][4], ka[2][4], va[2][4];
    #pragma unroll
    for (int s = 0; s < 2; ++s)
        #pragma unroll
        for (int n = 0; n < 4; ++n) { qa[s][n] = 0.f; ka[s][n] = 0.f; va[s][n] = 0.f; }
    {
        const float* wq0 = W_q + r0 * 4096 + c;
        const float* wk0 = W_k + r0 * 4096 + c;
        const float* wv0 = W_v + r0 * 4096 + c;
        const float* wq1 = W_q + r1 * 4096 + c;
        const float* wk1 = W_k + r1 * 4096 + c;
        const float* wv1 = W_v + r1 * 4096 + c;
        for (int d = 0; d < 128; d += 4) {
            float4 z0[4], z1[4];
            #pragma unroll
            for (int n = 0; n < 4; ++n) {
                z0[n] = *(const float4*)&agg[nbase + n][r0][d];
                z1[n] = *(const float4*)&agg[nbase + n][r1][d];
            }
            #pragma unroll
            for (int j = 0; j < 4; ++j) {
                float a0 = wq0[(d + j) * 32], b0 = wk0[(d + j) * 32], c0 = wv0[(d + j) * 32];
                float a1 = wq1[(d + j) * 32], b1 = wk1[(d + j) * 32], c1 = wv1[(d + j) * 32];
                #pragma unroll
                for (int n = 0; n < 4; ++n) {
                    float z0j = (&z0[n].x)[j], z1j = (&z1[n].x)[j];
                    qa[0][n] += z0j * a0; ka[0][n] += z0j * b0; va[0][n] += z0j * c0;
                    qa[1][n] += z1j * a1; ka[1][n] += z1j * b1; va[1][n] += z1j * c1;
                }
            }
        }
    }
    __syncthreads();   // overlay padded q/k/v onto agg region
    float* qs  = aggp;                      // [n][r][QS_]
    float* ks2 = aggp + NB_ * NS_;
    float* vs2 = aggp + 2 * NB_ * NS_;      // 6912 <= 8192
    #pragma unroll
    for (int s = 0; s < 2; ++s) {
        int rr = w + s * 4;
        #pragma unroll
        for (int n = 0; n < 4; ++n) {
            int base = (nbase + n) * NS_ + rr * QS_ + c;
            qs [base] = qa[s][n];
            ks2[base] = ka[s][n];
            vs2[base] = va[s][n];
        }
    }
    __syncthreads();

    // ---- psi[n][rr][ss] ----
    for (int idx = tid; idx < NB_ * 64; idx += 256) {
        int n = idx >> 6, rr = (idx >> 3) & 7, ss = idx & 7;
        const float4* q4 = (const float4*)&qs [n * NS_ + rr * QS_];
        const float4* k4 = (const float4*)&ks2[n * NS_ + ss * QS_];
        float p = 0.f;
        #pragma unroll
        for (int c4 = 0; c4 < 8; ++c4) {
            float4 a = q4[c4], b = k4[c4];
            p += a.x * b.x + a.y * b.y + a.z * b.z + a.w * b.w;
        }
        psi_l[idx] = p;
    }
    __syncthreads();
    if (tid < NB_ * 8) {
        float* row = &psi_l[tid * 8];
        float m = -INFINITY;
        #pragma unroll
        for (int s = 0; s < 8; ++s) m = fmaxf(m, row[s]);
        float sum = 0.f;
        #pragma unroll
        for (int s = 0; s < 8; ++s) { float e = __expf(row[s] - m); row[s] = e; sum += e; }
        float inv = 1.f / sum;
        #pragma unroll
        for (int s = 0; s < 8; ++s) row[s] *= inv;
    }
    __syncthreads();

    // ---- delta ----
    float dl[2][4];
    #pragma unroll
    for (int s = 0; s < 2; ++s)
        #pragma unroll
        for (int n = 0; n < 4; ++n) dl[s][n] = 0.f;
    #pragma unroll
    for (int s = 0; s < 8; ++s) {
        #pragma unroll
        for (int n = 0; n < 4; ++n) {
            float vv = vs2[(nbase + n) * NS_ + s * QS_ + c];
            dl[0][n] += psi_l[(nbase + n) * 64 + r0 * 8 + s] * vv;
            dl[1][n] += psi_l[(nbase + n) * 64 + r1 * 8 + s] * vv;
        }
    }
    __syncthreads();
    #pragma unroll
    for (int s = 0; s < 2; ++s) {
        int rr = w + s * 4;
        #pragma unroll
        for (int n = 0; n < 4; ++n)
            qs[(nbase + n) * NS_ + rr * QS_ + c] = dl[s][n];
    }
    __syncthreads();

    // ---- mask ----
    if (tid < NB_ * 8) {
        int n = tid >> 3, rr = tid & 7;
        float s = 0.f;
        #pragma unroll
        for (int cc = 0; cc < 32; ++cc) s += qs[n * NS_ + rr * QS_ + cc];
        mskl[tid] = (s != 0.f) ? 1.f : 0.f;
    }
    __syncthreads();

    // ---- out ----
    {
        int n = tid >> 5, cc = tid & 31;
        if (n0 + n < N) {
            float st = out[(size_t)(n0 + n) * 32 + cc];
            float o = 0.f;
            #pragma unroll
            for (int rr = 0; rr < 8; ++rr)
                o += (qs[n * NS_ + rr * QS_ + cc] + st * mskl[n * 8 + rr]) * W_rel[rr];
            out[(size_t)(n0 + n) * 32 + cc] = o;
        }
    }
}

// -------------------------------------------------------------------------
extern "C" void kernel_launch(void* const* d_in, const int* in_sizes, int n_in,
                              void* d_out, int out_size, void* d_ws, size_t ws_size,
                              hipStream_t stream)
{
    const float* x      = (const float*)d_in[0];
    const int*   ei     = (const int*)  d_in[1];   // [2,E]
    const int*   et     = (const int*)  d_in[2];   // [E]
    const float* Wj     = (const float*)d_in[3];
    const float* Wi     = (const float*)d_in[4];
    const float* natt   = (const float*)d_in[5];
    const float* W_q    = (const float*)d_in[6];
    const float* W_k    = (const float*)d_in[7];
    const float* W_v    = (const float*)d_in[8];
    const float* W_self = (const float*)d_in[9];
    const float* W_sn   = (const float*)d_in[10];
    const float* W_rel  = (const float*)d_in[11];
    float* out = (float*)d_out;

    const int N = in_sizes[0] / INF_;
    const int E = in_sizes[2];
    const int G = (N + NB_ - 1) / NB_;   // 8-node groups

    // workspace layout (~156 MB)
    float* ws        = (float*)d_ws;
    float* self_node = ws;                               // N*128
    float* AI        = self_node + (size_t)N * 128;      // N*32
    float* AJ        = AI + (size_t)N * 32;              // N*32
    float* M_i       = AJ + (size_t)N * 32;              // 128*32
    float* M_j       = M_i + 128 * 32;                   // 128*32
    unsigned short* hjb = (unsigned short*)(M_j + 128 * 32);  // N*128 fp16
    unsigned short* zg  = hjb + (size_t)N * 128;         // N*1024 fp16
    int*   counts    = (int*)(zg + (size_t)N * 1024);    // G+1
    int*   offsets   = counts + (G + 1);                 // G+1
    int*   cursor    = offsets + (G + 1);                // G
    int*   sorted    = cursor + G;                       // E

    // ---- CSR build ----
    hipMemsetAsync(counts, 0, (size_t)(G + 1) * sizeof(int), stream);
    count_edges<<<(E + 255) / 256, 256, 0, stream>>>(ei, counts, E);
    scan_offsets<<<1, 1024, 0, stream>>>(counts, offsets, G);
    hipMemcpyAsync(cursor, offsets, (size_t)G * sizeof(int),
                   hipMemcpyDeviceToDevice, stream);
    scatter_edges<<<(E + 255) / 256, 256, 0, stream>>>(ei, et, cursor, sorted, E);

    // ---- node feature GEMMs ----
    prep_M<<<32, 256, 0, stream>>>(Wi, Wj, natt, M_i, M_j);
    dim3 gA((N + 31) / 32, 11);
    fused_gemm<<<gA, 256, 0, stream>>>(x, Wj, W_sn, W_self, M_i, M_j,
                                       hjb, self_node, out, AI, AJ, N);

    // ---- phase 1: edge aggregation -> z ----
    edge_z<<<G, 256, 0, stream>>>(hjb, self_node, AJ, AI, offsets, sorted, zg, N);

    // ---- phase 2: tail ----
    node_tail<<<G, 256, 0, stream>>>(zg, W_q, W_k, W_v, W_rel, out, N);
}

// Round 9
// 808.092 us; speedup vs baseline: 1.9983x; 1.0922x over previous
//
#include <hip/hip_runtime.h>
#include <hip/hip_fp16.h>
#include <math.h>

constexpr int INF_ = 128;  // IN
constexpr int H_   = 4;
constexpr int C_   = 32;
constexpr int R_   = 8;
constexpr int NB_  = 8;    // nodes per block
constexpr int QS_  = 36;   // padded row stride for q/k/v in LDS
constexpr int NS_  = R_ * QS_;   // 288 floats per node
constexpr int EMAX_ = 320; // staged edges per block (mean 102)

__device__ __forceinline__ unsigned short f2h(float f) {
    return __half_as_ushort(__float2half(f));
}
__device__ __forceinline__ float h2f(unsigned short u) {
    return __half2float(__ushort_as_half(u));
}

// -------------------------------------------------------------------------
// CSR build at 8-node GROUP granularity.
// -------------------------------------------------------------------------
__global__ __launch_bounds__(256) void count_edges(
    const int* __restrict__ ei, int* __restrict__ counts, int E)
{
    int e = blockIdx.x * 256 + threadIdx.x;
    if (e >= E) return;
    int dst = ei[E + e];
    atomicAdd(&counts[dst >> 3], 1);
}

__global__ __launch_bounds__(1024) void scan_offsets(
    const int* __restrict__ counts, int* __restrict__ offsets, int G)
{
    __shared__ int wsum[16];
    __shared__ int chunk_tot;
    const int tid  = threadIdx.x;
    const int lane = tid & 63;
    const int wid  = tid >> 6;
    int carry = 0;
    for (int base = 0; base < G; base += 1024) {
        int i = base + tid;
        int v = (i < G) ? counts[i] : 0;
        int s = v;
        #pragma unroll
        for (int d = 1; d < 64; d <<= 1) {
            int t = __shfl_up(s, d, 64);
            if (lane >= d) s += t;
        }
        if (lane == 63) wsum[wid] = s;
        __syncthreads();
        if (tid == 0) {
            int acc = 0;
            #pragma unroll
            for (int w = 0; w < 16; ++w) { int t = wsum[w]; wsum[w] = acc; acc += t; }
            chunk_tot = acc;
        }
        __syncthreads();
        int excl = carry + wsum[wid] + (s - v);
        if (i < G) offsets[i] = excl;
        carry += chunk_tot;
        __syncthreads();
    }
    if (tid == 0) offsets[G] = carry;
}

// packed: src | r<<17 | (dst&7)<<20
__global__ __launch_bounds__(256) void scatter_edges(
    const int* __restrict__ ei, const int* __restrict__ et,
    int* __restrict__ cursor, int* __restrict__ sorted, int E)
{
    int e = blockIdx.x * 256 + threadIdx.x;
    if (e >= E) return;
    int src = ei[e];
    int dst = ei[E + e];
    int r   = et[e];
    int pos = atomicAdd(&cursor[dst >> 3], 1);
    sorted[pos] = src | (r << 17) | ((dst & 7) << 20);
}

// -------------------------------------------------------------------------
// M_i[d][r*4+h] = sum_c Wi[d][h*32+c] * natt[r*4+h][c]
// M_j[d][r*4+h] = sum_c Wj[d][h*32+c] * natt[r*4+h][32+c]
// -------------------------------------------------------------------------
__global__ __launch_bounds__(256) void prep_M(
    const float* __restrict__ Wi, const float* __restrict__ Wj,
    const float* __restrict__ natt,
    float* __restrict__ M_i, float* __restrict__ M_j)
{
    int idx = blockIdx.x * 256 + threadIdx.x;   // 0..8191
    int which = idx >> 12;
    int d  = (idx >> 5) & 127;
    int rh = idx & 31;
    int h  = rh & 3;
    const float* W   = which ? Wj : Wi;
    const float* att = natt + rh * 64 + (which ? 32 : 0);
    float acc = 0.f;
    #pragma unroll
    for (int c = 0; c < 32; ++c)
        acc += W[d * 128 + h * 32 + c] * att[c];
    (which ? M_j : M_i)[d * 32 + rh] = acc;
}

// -------------------------------------------------------------------------
// Fused node GEMMs — x tile read ONCE per block, all 11 col-groups inside.
//   cg 0..3  : h_j (fp16 swizzled: hjb[node*128 + c_local*4 + cg])
//   cg 4..7  : self_node fp16
//   cg 8     : self_term fp32 -> d_out
//   cg 9     : AI fp32, cg 10: AJ fp32
// -------------------------------------------------------------------------
__global__ __launch_bounds__(256) void fused_gemm(
    const float* __restrict__ x,
    const float* __restrict__ Wj,
    const float* __restrict__ Wsn,
    const float* __restrict__ Wself,
    const float* __restrict__ M_i,
    const float* __restrict__ M_j,
    unsigned short* __restrict__ hjb,   // [N*128] fp16 swizzled
    unsigned short* __restrict__ sn16,  // [N*128] fp16
    float* __restrict__ self_term,      // = d_out
    float* __restrict__ AI,
    float* __restrict__ AJ,
    int N)
{
    __shared__ float xs[32][128];
    const int n0  = blockIdx.x * 32;
    const int tid = threadIdx.x;

    #pragma unroll
    for (int j = 0; j < 4; ++j) {
        int f4   = tid + 256 * j;
        int row  = f4 >> 5;
        int col4 = f4 & 31;
        float4 v = make_float4(0.f, 0.f, 0.f, 0.f);
        if (n0 + row < N)
            v = *(const float4*)(x + (size_t)(n0 + row) * 128 + col4 * 4);
        *(float4*)(&xs[row][col4 * 4]) = v;
    }
    __syncthreads();

    const int c_local = tid & 31;
    const int n_base  = tid >> 5;
    const bool ok0 = (n0 + n_base      < N);
    const bool ok1 = (n0 + n_base +  8 < N);
    const bool ok2 = (n0 + n_base + 16 < N);
    const bool ok3 = (n0 + n_base + 24 < N);

    for (int cg = 0; cg < 11; ++cg) {
        const int col = cg * 32 + c_local;
        const float* W; int wcol, wstride;
        if (col < 128)      { W = Wj;    wcol = col;       wstride = 128; }
        else if (col < 256) { W = Wsn;   wcol = col - 128; wstride = 128; }
        else if (col < 288) { W = Wself; wcol = col - 256; wstride = 32;  }
        else if (col < 320) { W = M_i;   wcol = col - 288; wstride = 32;  }
        else                { W = M_j;   wcol = col - 320; wstride = 32;  }

        float acc0 = 0.f, acc1 = 0.f, acc2 = 0.f, acc3 = 0.f;
        for (int k = 0; k < 128; k += 4) {
            float4 x0 = *(const float4*)&xs[n_base     ][k];
            float4 x1 = *(const float4*)&xs[n_base +  8][k];
            float4 x2 = *(const float4*)&xs[n_base + 16][k];
            float4 x3 = *(const float4*)&xs[n_base + 24][k];
            float w0 = W[(k + 0) * wstride + wcol];
            float w1 = W[(k + 1) * wstride + wcol];
            float w2 = W[(k + 2) * wstride + wcol];
            float w3 = W[(k + 3) * wstride + wcol];
            acc0 += x0.x * w0 + x0.y * w1 + x0.z * w2 + x0.w * w3;
            acc1 += x1.x * w0 + x1.y * w1 + x1.z * w2 + x1.w * w3;
            acc2 += x2.x * w0 + x2.y * w1 + x2.z * w2 + x2.w * w3;
            acc3 += x3.x * w0 + x3.y * w1 + x3.z * w2 + x3.w * w3;
        }

        if (cg < 4) {
            int so = c_local * 4 + cg;   // swizzle
            if (ok0) hjb[(size_t)(n0 + n_base     ) * 128 + so] = f2h(acc0);
            if (ok1) hjb[(size_t)(n0 + n_base +  8) * 128 + so] = f2h(acc1);
            if (ok2) hjb[(size_t)(n0 + n_base + 16) * 128 + so] = f2h(acc2);
            if (ok3) hjb[(size_t)(n0 + n_base + 24) * 128 + so] = f2h(acc3);
        } else if (cg < 8) {
            if (ok0) sn16[(size_t)(n0 + n_base     ) * 128 + wcol] = f2h(acc0);
            if (ok1) sn16[(size_t)(n0 + n_base +  8) * 128 + wcol] = f2h(acc1);
            if (ok2) sn16[(size_t)(n0 + n_base + 16) * 128 + wcol] = f2h(acc2);
            if (ok3) sn16[(size_t)(n0 + n_base + 24) * 128 + wcol] = f2h(acc3);
        } else {
            float* outb = (cg == 8) ? self_term : (cg == 9) ? AI : AJ;
            if (ok0) outb[(size_t)(n0 + n_base     ) * 32 + wcol] = acc0;
            if (ok1) outb[(size_t)(n0 + n_base +  8) * 32 + wcol] = acc1;
            if (ok2) outb[(size_t)(n0 + n_base + 16) * 32 + wcol] = acc2;
            if (ok3) outb[(size_t)(n0 + n_base + 24) * 32 + wcol] = acc3;
        }
    }
}

// -------------------------------------------------------------------------
// PHASE 1: edge aggregation -> z (fp16, global). Counting-sort in LDS by
// (node,r); register-accumulated runs; one LDS-atomic flush per run.
// -------------------------------------------------------------------------
__global__ __launch_bounds__(256) void edge_z(
    const unsigned short* __restrict__ hjb,  // [N*128] fp16 swizzled
    const unsigned short* __restrict__ sn16, // [N*128] fp16
    const float* __restrict__ AJ,        // [N,32]
    const float* __restrict__ AI,        // [N,32]
    const int*   __restrict__ offsets,   // [G+1]
    const int*   __restrict__ sorted,    // [E]
    unsigned short* __restrict__ zg,     // [N*1024] fp16: z[n][r][d]
    int N)
{
    __shared__ float agg[NB_][R_][128];   // 32 KB
    __shared__ float den[NB_][R_][H_];    // 1 KB
    __shared__ float ai [NB_][32];        // 1 KB
    __shared__ int   ebuf[EMAX_];
    __shared__ int   sbuf[EMAX_];
    __shared__ int   bstart[64];
    __shared__ int   bcur[64];

    const int tid = threadIdx.x;
    const int n0  = blockIdx.x * NB_;
    float* aggp = &agg[0][0][0];

    const int e0 = offsets[blockIdx.x];
    const int e1 = offsets[blockIdx.x + 1];
    const int ecount_raw = e1 - e0;
    const int ecount = (ecount_raw < EMAX_) ? ecount_raw : EMAX_;

    for (int i4 = tid; i4 < NB_ * R_ * 32; i4 += 256)
        ((float4*)aggp)[i4] = make_float4(0.f, 0.f, 0.f, 0.f);
    (&den[0][0][0])[tid] = 0.f;                     // NB*R*H == 256
    {
        int nl = tid >> 5, rh = tid & 31;
        ai[nl][rh] = (n0 + nl < N) ? AI[(size_t)(n0 + nl) * 32 + rh] : 0.f;
    }
    if (tid < 64) bstart[tid] = 0;
    for (int i = tid; i < ecount; i += 256) ebuf[i] = sorted[e0 + i];
    __syncthreads();

    for (int i = tid; i < ecount; i += 256) {
        int pk = ebuf[i];
        int key = (((pk >> 20) & 7) << 3) | ((pk >> 17) & 7);
        atomicAdd(&bstart[key], 1);
    }
    __syncthreads();
    if (tid < 64) {
        int v = bstart[tid];
        int s = v;
        #pragma unroll
        for (int d = 1; d < 64; d <<= 1) {
            int t = __shfl_up(s, d, 64);
            if (tid >= d) s += t;
        }
        bstart[tid] = s - v;
        bcur[tid]   = s - v;
    }
    __syncthreads();
    for (int i = tid; i < ecount; i += 256) {
        int pk = ebuf[i];
        int key = (((pk >> 20) & 7) << 3) | ((pk >> 17) & 7);
        int pos = atomicAdd(&bcur[key], 1);
        sbuf[pos] = pk;
    }
    __syncthreads();

    // register-accumulated walk: half-wave = one node
    {
        const int nl = tid >> 5;
        const int l  = tid & 31;
        int s_ = bstart[nl * 8];
        int t_ = (nl == 7) ? ecount : bstart[nl * 8 + 8];

        int cur_r = -1;
        float acc0 = 0.f, acc1 = 0.f, acc2 = 0.f, acc3 = 0.f;
        float dn0 = 0.f, dn1 = 0.f, dn2 = 0.f, dn3 = 0.f;

        int pk = 0, src = 0, r = 0;
        ushort4 hv = make_ushort4(0,0,0,0);
        float4  aj = make_float4(0.f,0.f,0.f,0.f);
        if (s_ < t_) {
            pk = sbuf[s_]; src = pk & 0x1FFFF; r = (pk >> 17) & 7;
            hv = *(const ushort4*)(hjb + (size_t)src * 128 + l * 4);
            aj = *(const float4*)(AJ + (size_t)src * 32 + r * 4);
        }
        for (int e = s_; e < t_; ++e) {
            int pk2 = 0, src2 = 0, r2 = 0;
            ushort4 hv2 = hv; float4 aj2 = aj;
            if (e + 1 < t_) {
                pk2 = sbuf[e + 1]; src2 = pk2 & 0x1FFFF; r2 = (pk2 >> 17) & 7;
                hv2 = *(const ushort4*)(hjb + (size_t)src2 * 128 + l * 4);
                aj2 = *(const float4*)(AJ + (size_t)src2 * 32 + r2 * 4);
            }
            if (r != cur_r) {
                if (cur_r >= 0) {
                    float* dp = &agg[nl][cur_r][l];
                    atomicAdd(dp,      acc0); atomicAdd(dp + 32, acc1);
                    atomicAdd(dp + 64, acc2); atomicAdd(dp + 96, acc3);
                    if (l < 4) {
                        float dv = (l == 0) ? dn0 : (l == 1) ? dn1 : (l == 2) ? dn2 : dn3;
                        atomicAdd(&den[nl][cur_r][l], dv);
                    }
                }
                cur_r = r;
                acc0 = acc1 = acc2 = acc3 = 0.f;
                dn0 = dn1 = dn2 = dn3 = 0.f;
            }
            const float* aip = &ai[nl][r * 4];
            float a0 = aip[0] + aj.x; a0 = (a0 > 0.f) ? a0 : 0.2f * a0;
            float a1 = aip[1] + aj.y; a1 = (a1 > 0.f) ? a1 : 0.2f * a1;
            float a2 = aip[2] + aj.z; a2 = (a2 > 0.f) ? a2 : 0.2f * a2;
            float a3 = aip[3] + aj.w; a3 = (a3 > 0.f) ? a3 : 0.2f * a3;
            float x0 = __expf(a0), x1 = __expf(a1), x2 = __expf(a2), x3 = __expf(a3);
            dn0 += x0; dn1 += x1; dn2 += x2; dn3 += x3;
            acc0 += x0 * h2f(hv.x); acc1 += x1 * h2f(hv.y);
            acc2 += x2 * h2f(hv.z); acc3 += x3 * h2f(hv.w);
            pk = pk2; src = src2; r = r2; hv = hv2; aj = aj2;
        }
        if (cur_r >= 0) {
            float* dp = &agg[nl][cur_r][l];
            atomicAdd(dp,      acc0); atomicAdd(dp + 32, acc1);
            atomicAdd(dp + 64, acc2); atomicAdd(dp + 96, acc3);
            if (l < 4) {
                float dv = (l == 0) ? dn0 : (l == 1) ? dn1 : (l == 2) ? dn2 : dn3;
                atomicAdd(&den[nl][cur_r][l], dv);
            }
        }
    }
    // overflow fallback
    if (ecount_raw > EMAX_) {
        const int slot = tid >> 5;
        const int l    = tid & 31;
        for (int k = e0 + EMAX_ + slot; k < e1; k += 8) {
            int pk  = sorted[k];
            int src = pk & 0x1FFFF;
            int r   = (pk >> 17) & 7;
            int nl  = (pk >> 20) & 7;
            ushort4 hv = *(const ushort4*)(hjb + (size_t)src * 128 + l * 4);
            float4  aj = *(const float4*)(AJ + (size_t)src * 32 + r * 4);
            const float* aip = &ai[nl][r * 4];
            float a0 = aip[0] + aj.x; a0 = (a0 > 0.f) ? a0 : 0.2f * a0;
            float a1 = aip[1] + aj.y; a1 = (a1 > 0.f) ? a1 : 0.2f * a1;
            float a2 = aip[2] + aj.z; a2 = (a2 > 0.f) ? a2 : 0.2f * a2;
            float a3 = aip[3] + aj.w; a3 = (a3 > 0.f) ? a3 : 0.2f * a3;
            float x0 = __expf(a0), x1 = __expf(a1), x2 = __expf(a2), x3 = __expf(a3);
            if (l < 4) {
                float myex = (l == 0) ? x0 : (l == 1) ? x1 : (l == 2) ? x2 : x3;
                atomicAdd(&den[nl][r][l], myex);
            }
            float* dp = &agg[nl][r][l];
            atomicAdd(dp,      x0 * h2f(hv.x));
            atomicAdd(dp + 32, x1 * h2f(hv.y));
            atomicAdd(dp + 64, x2 * h2f(hv.z));
            atomicAdd(dp + 96, x3 * h2f(hv.w));
        }
    }
    __syncthreads();

    // z = agg/(den+eps) + self_node -> fp16 global
    for (int i4 = tid; i4 < NB_ * R_ * 32; i4 += 256) {
        int nl  = i4 >> 8;
        int rr  = (i4 >> 5) & 7;
        int hc4 = i4 & 31;
        int h   = hc4 >> 3;
        float invd = 1.f / (den[nl][rr][h] + 1e-16f);
        float4 a4 = ((float4*)aggp)[i4];
        a4.x *= invd; a4.y *= invd; a4.z *= invd; a4.w *= invd;
        if (n0 + nl < N) {
            ushort4 s4 = *(const ushort4*)(sn16 + (size_t)(n0 + nl) * 128 + hc4 * 4);
            a4.x += h2f(s4.x); a4.y += h2f(s4.y); a4.z += h2f(s4.z); a4.w += h2f(s4.w);
            ushort4 u;
            u.x = f2h(a4.x); u.y = f2h(a4.y); u.z = f2h(a4.z); u.w = f2h(a4.w);
            *(ushort4*)(zg + (size_t)(n0 + nl) * 1024 + rr * 128 + hc4 * 4) = u;
        }
    }
}

// -------------------------------------------------------------------------
// PHASE 2: z -> qkv -> psi softmax -> delta -> out.  256 thr / 8 nodes.
// -------------------------------------------------------------------------
__global__ __launch_bounds__(256) void node_tail(
    const unsigned short* __restrict__ zg,   // [N*1024] fp16
    const float* __restrict__ W_q,       // [R,128,32]
    const float* __restrict__ W_k,
    const float* __restrict__ W_v,
    const float* __restrict__ W_rel,     // [R]
    float* __restrict__ out,             // [N,32]; holds self_term on entry
    int N)
{
    __shared__ float agg[NB_][R_][128];   // 32 KB; overlaid with padded q/k/v
    __shared__ float psi_l[NB_ * 64];     // 2 KB
    __shared__ float mskl[NB_ * 8];       // 256 B

    const int tid = threadIdx.x;
    const int n0  = blockIdx.x * NB_;
    float* aggp = &agg[0][0][0];

    for (int i4 = tid; i4 < NB_ * R_ * 32; i4 += 256) {
        int nl = i4 >> 8;
        float4 f;
        if (n0 + nl < N) {
            ushort4 u = *(const ushort4*)(zg + (size_t)(n0 + nl) * 1024 + (i4 & 255) * 4);
            f.x = h2f(u.x); f.y = h2f(u.y); f.z = h2f(u.z); f.w = h2f(u.w);
        } else f = make_float4(0.f, 0.f, 0.f, 0.f);
        ((float4*)aggp)[i4] = f;
    }
    __syncthreads();

    const int w    = tid >> 6;
    const int lane = tid & 63;
    const int c    = lane & 31;
    const int nh   = lane >> 5;
    const int r0   = w, r1 = w + 4;
    const int nbase = nh * 4;

    float qa[2][4], ka[2][4], va[2][4];
    #pragma unroll
    for (int s = 0; s < 2; ++s)
        #pragma unroll
        for (int n = 0; n < 4; ++n) { qa[s][n] = 0.f; ka[s][n] = 0.f; va[s][n] = 0.f; }
    {
        const float* wq0 = W_q + r0 * 4096 + c;
        const float* wk0 = W_k + r0 * 4096 + c;
        const float* wv0 = W_v + r0 * 4096 + c;
        const float* wq1 = W_q + r1 * 4096 + c;
        const float* wk1 = W_k + r1 * 4096 + c;
        const float* wv1 = W_v + r1 * 4096 + c;
        for (int d = 0; d < 128; d += 4) {
            float4 z0[4], z1[4];
            #pragma unroll
            for (int n = 0; n < 4; ++n) {
                z0[n] = *(const float4*)&agg[nbase + n][r0][d];
                z1[n] = *(const float4*)&agg[nbase + n][r1][d];
            }
            #pragma unroll
            for (int j = 0; j < 4; ++j) {
                float a0 = wq0[(d + j) * 32], b0 = wk0[(d + j) * 32], c0 = wv0[(d + j) * 32];
                float a1 = wq1[(d + j) * 32], b1 = wk1[(d + j) * 32], c1 = wv1[(d + j) * 32];
                #pragma unroll
                for (int n = 0; n < 4; ++n) {
                    float z0j = (&z0[n].x)[j], z1j = (&z1[n].x)[j];
                    qa[0][n] += z0j * a0; ka[0][n] += z0j * b0; va[0][n] += z0j * c0;
                    qa[1][n] += z1j * a1; ka[1][n] += z1j * b1; va[1][n] += z1j * c1;
                }
            }
        }
    }
    __syncthreads();
    float* qs  = aggp;
    float* ks2 = aggp + NB_ * NS_;
    float* vs2 = aggp + 2 * NB_ * NS_;
    #pragma unroll
    for (int s = 0; s < 2; ++s) {
        int rr = w + s * 4;
        #pragma unroll
        for (int n = 0; n < 4; ++n) {
            int base = (nbase + n) * NS_ + rr * QS_ + c;
            qs [base] = qa[s][n];
            ks2[base] = ka[s][n];
            vs2[base] = va[s][n];
        }
    }
    __syncthreads();

    for (int idx = tid; idx < NB_ * 64; idx += 256) {
        int n = idx >> 6, rr = (idx >> 3) & 7, ss = idx & 7;
        const float4* q4 = (const float4*)&qs [n * NS_ + rr * QS_];
        const float4* k4 = (const float4*)&ks2[n * NS_ + ss * QS_];
        float p = 0.f;
        #pragma unroll
        for (int c4 = 0; c4 < 8; ++c4) {
            float4 a = q4[c4], b = k4[c4];
            p += a.x * b.x + a.y * b.y + a.z * b.z + a.w * b.w;
        }
        psi_l[idx] = p;
    }
    __syncthreads();
    if (tid < NB_ * 8) {
        float* row = &psi_l[tid * 8];
        float m = -INFINITY;
        #pragma unroll
        for (int s = 0; s < 8; ++s) m = fmaxf(m, row[s]);
        float sum = 0.f;
        #pragma unroll
        for (int s = 0; s < 8; ++s) { float e = __expf(row[s] - m); row[s] = e; sum += e; }
        float inv = 1.f / sum;
        #pragma unroll
        for (int s = 0; s < 8; ++s) row[s] *= inv;
    }
    __syncthreads();

    float dl[2][4];
    #pragma unroll
    for (int s = 0; s < 2; ++s)
        #pragma unroll
        for (int n = 0; n < 4; ++n) dl[s][n] = 0.f;
    #pragma unroll
    for (int s = 0; s < 8; ++s) {
        #pragma unroll
        for (int n = 0; n < 4; ++n) {
            float vv = vs2[(nbase + n) * NS_ + s * QS_ + c];
            dl[0][n] += psi_l[(nbase + n) * 64 + r0 * 8 + s] * vv;
            dl[1][n] += psi_l[(nbase + n) * 64 + r1 * 8 + s] * vv;
        }
    }
    __syncthreads();
    #pragma unroll
    for (int s = 0; s < 2; ++s) {
        int rr = w + s * 4;
        #pragma unroll
        for (int n = 0; n < 4; ++n)
            qs[(nbase + n) * NS_ + rr * QS_ + c] = dl[s][n];
    }
    __syncthreads();

    if (tid < NB_ * 8) {
        int n = tid >> 3, rr = tid & 7;
        float s = 0.f;
        #pragma unroll
        for (int cc = 0; cc < 32; ++cc) s += qs[n * NS_ + rr * QS_ + cc];
        mskl[tid] = (s != 0.f) ? 1.f : 0.f;
    }
    __syncthreads();

    {
        int n = tid >> 5, cc = tid & 31;
        if (n0 + n < N) {
            float st = out[(size_t)(n0 + n) * 32 + cc];
            float o = 0.f;
            #pragma unroll
            for (int rr = 0; rr < 8; ++rr)
                o += (qs[n * NS_ + rr * QS_ + cc] + st * mskl[n * 8 + rr]) * W_rel[rr];
            out[(size_t)(n0 + n) * 32 + cc] = o;
        }
    }
}

// -------------------------------------------------------------------------
extern "C" void kernel_launch(void* const* d_in, const int* in_sizes, int n_in,
                              void* d_out, int out_size, void* d_ws, size_t ws_size,
                              hipStream_t stream)
{
    const float* x      = (const float*)d_in[0];
    const int*   ei     = (const int*)  d_in[1];   // [2,E]
    const int*   et     = (const int*)  d_in[2];   // [E]
    const float* Wj     = (const float*)d_in[3];
    const float* Wi     = (const float*)d_in[4];
    const float* natt   = (const float*)d_in[5];
    const float* W_q    = (const float*)d_in[6];
    const float* W_k    = (const float*)d_in[7];
    const float* W_v    = (const float*)d_in[8];
    const float* W_self = (const float*)d_in[9];
    const float* W_sn   = (const float*)d_in[10];
    const float* W_rel  = (const float*)d_in[11];
    float* out = (float*)d_out;

    const int N = in_sizes[0] / INF_;
    const int E = in_sizes[2];
    const int G = (N + NB_ - 1) / NB_;   // 8-node groups

    // workspace layout (~145 MB)
    float* ws        = (float*)d_ws;
    float* AI        = ws;                               // N*32
    float* AJ        = AI + (size_t)N * 32;              // N*32
    float* M_i       = AJ + (size_t)N * 32;              // 128*32
    float* M_j       = M_i + 128 * 32;                   // 128*32
    unsigned short* hjb  = (unsigned short*)(M_j + 128 * 32);  // N*128 fp16
    unsigned short* sn16 = hjb + (size_t)N * 128;        // N*128 fp16
    unsigned short* zg   = sn16 + (size_t)N * 128;       // N*1024 fp16
    int*   counts    = (int*)(zg + (size_t)N * 1024);    // G+1
    int*   offsets   = counts + (G + 1);                 // G+1
    int*   cursor    = offsets + (G + 1);                // G
    int*   sorted    = cursor + G;                       // E

    // ---- CSR build ----
    hipMemsetAsync(counts, 0, (size_t)(G + 1) * sizeof(int), stream);
    count_edges<<<(E + 255) / 256, 256, 0, stream>>>(ei, counts, E);
    scan_offsets<<<1, 1024, 0, stream>>>(counts, offsets, G);
    hipMemcpyAsync(cursor, offsets, (size_t)G * sizeof(int),
                   hipMemcpyDeviceToDevice, stream);
    scatter_edges<<<(E + 255) / 256, 256, 0, stream>>>(ei, et, cursor, sorted, E);

    // ---- node feature GEMMs (x read once) ----
    prep_M<<<32, 256, 0, stream>>>(Wi, Wj, natt, M_i, M_j);
    fused_gemm<<<(N + 31) / 32, 256, 0, stream>>>(
        x, Wj, W_sn, W_self, M_i, M_j, hjb, sn16, out, AI, AJ, N);

    // ---- phase 1: edge aggregation -> z ----
    edge_z<<<G, 256, 0, stream>>>(hjb, sn16, AJ, AI, offsets, sorted, zg, N);

    // ---- phase 2: tail ----
    node_tail<<<G, 256, 0, stream>>>(zg, W_q, W_k, W_v, W_rel, out, N);
}

// Round 10
// 771.933 us; speedup vs baseline: 2.0919x; 1.0468x over previous
//
#include <hip/hip_runtime.h>
#include <hip/hip_fp16.h>
#include <math.h>

constexpr int INF_ = 128;  // IN
constexpr int H_   = 4;
constexpr int C_   = 32;
constexpr int R_   = 8;
constexpr int NB_  = 8;    // nodes per block
constexpr int QS_  = 36;   // padded row stride for q/k/v in LDS
constexpr int NS_  = R_ * QS_;   // 288 floats per node
constexpr int EMAX_ = 320; // staged edges per block (mean 102)

__device__ __forceinline__ unsigned short f2h(float f) {
    return __half_as_ushort(__float2half(f));
}
__device__ __forceinline__ float h2f(unsigned short u) {
    return __half2float(__ushort_as_half(u));
}

// -------------------------------------------------------------------------
// CSR build at 8-node GROUP granularity.
// -------------------------------------------------------------------------
__global__ __launch_bounds__(256) void count_edges(
    const int* __restrict__ ei, int* __restrict__ counts, int E)
{
    int e = blockIdx.x * 256 + threadIdx.x;
    if (e >= E) return;
    int dst = ei[E + e];
    atomicAdd(&counts[dst >> 3], 1);
}

__global__ __launch_bounds__(1024) void scan_offsets(
    const int* __restrict__ counts, int* __restrict__ offsets, int G)
{
    __shared__ int wsum[16];
    __shared__ int chunk_tot;
    const int tid  = threadIdx.x;
    const int lane = tid & 63;
    const int wid  = tid >> 6;
    int carry = 0;
    for (int base = 0; base < G; base += 1024) {
        int i = base + tid;
        int v = (i < G) ? counts[i] : 0;
        int s = v;
        #pragma unroll
        for (int d = 1; d < 64; d <<= 1) {
            int t = __shfl_up(s, d, 64);
            if (lane >= d) s += t;
        }
        if (lane == 63) wsum[wid] = s;
        __syncthreads();
        if (tid == 0) {
            int acc = 0;
            #pragma unroll
            for (int w = 0; w < 16; ++w) { int t = wsum[w]; wsum[w] = acc; acc += t; }
            chunk_tot = acc;
        }
        __syncthreads();
        int excl = carry + wsum[wid] + (s - v);
        if (i < G) offsets[i] = excl;
        carry += chunk_tot;
        __syncthreads();
    }
    if (tid == 0) offsets[G] = carry;
}

// packed: src | r<<17 | (dst&7)<<20
__global__ __launch_bounds__(256) void scatter_edges(
    const int* __restrict__ ei, const int* __restrict__ et,
    int* __restrict__ cursor, int* __restrict__ sorted, int E)
{
    int e = blockIdx.x * 256 + threadIdx.x;
    if (e >= E) return;
    int src = ei[e];
    int dst = ei[E + e];
    int r   = et[e];
    int pos = atomicAdd(&cursor[dst >> 3], 1);
    sorted[pos] = src | (r << 17) | ((dst & 7) << 20);
}

// -------------------------------------------------------------------------
// M_i[d][r*4+h] = sum_c Wi[d][h*32+c] * natt[r*4+h][c]
// M_j[d][r*4+h] = sum_c Wj[d][h*32+c] * natt[r*4+h][32+c]
// -------------------------------------------------------------------------
__global__ __launch_bounds__(256) void prep_M(
    const float* __restrict__ Wi, const float* __restrict__ Wj,
    const float* __restrict__ natt,
    float* __restrict__ M_i, float* __restrict__ M_j)
{
    int idx = blockIdx.x * 256 + threadIdx.x;   // 0..8191
    int which = idx >> 12;
    int d  = (idx >> 5) & 127;
    int rh = idx & 31;
    int h  = rh & 3;
    const float* W   = which ? Wj : Wi;
    const float* att = natt + rh * 64 + (which ? 32 : 0);
    float acc = 0.f;
    #pragma unroll
    for (int c = 0; c < 32; ++c)
        acc += W[d * 128 + h * 32 + c] * att[c];
    (which ? M_j : M_i)[d * 32 + rh] = acc;
}

// -------------------------------------------------------------------------
// Fused node GEMMs — x tile read ONCE per block, all 11 col-groups inside.
// -------------------------------------------------------------------------
__global__ __launch_bounds__(256) void fused_gemm(
    const float* __restrict__ x,
    const float* __restrict__ Wj,
    const float* __restrict__ Wsn,
    const float* __restrict__ Wself,
    const float* __restrict__ M_i,
    const float* __restrict__ M_j,
    unsigned short* __restrict__ hjb,   // [N*128] fp16 swizzled
    unsigned short* __restrict__ sn16,  // [N*128] fp16
    float* __restrict__ self_term,      // = d_out
    float* __restrict__ AI,
    float* __restrict__ AJ,
    int N)
{
    __shared__ float xs[32][128];
    const int n0  = blockIdx.x * 32;
    const int tid = threadIdx.x;

    #pragma unroll
    for (int j = 0; j < 4; ++j) {
        int f4   = tid + 256 * j;
        int row  = f4 >> 5;
        int col4 = f4 & 31;
        float4 v = make_float4(0.f, 0.f, 0.f, 0.f);
        if (n0 + row < N)
            v = *(const float4*)(x + (size_t)(n0 + row) * 128 + col4 * 4);
        *(float4*)(&xs[row][col4 * 4]) = v;
    }
    __syncthreads();

    const int c_local = tid & 31;
    const int n_base  = tid >> 5;
    const bool ok0 = (n0 + n_base      < N);
    const bool ok1 = (n0 + n_base +  8 < N);
    const bool ok2 = (n0 + n_base + 16 < N);
    const bool ok3 = (n0 + n_base + 24 < N);

    for (int cg = 0; cg < 11; ++cg) {
        const int col = cg * 32 + c_local;
        const float* W; int wcol, wstride;
        if (col < 128)      { W = Wj;    wcol = col;       wstride = 128; }
        else if (col < 256) { W = Wsn;   wcol = col - 128; wstride = 128; }
        else if (col < 288) { W = Wself; wcol = col - 256; wstride = 32;  }
        else if (col < 320) { W = M_i;   wcol = col - 288; wstride = 32;  }
        else                { W = M_j;   wcol = col - 320; wstride = 32;  }

        float acc0 = 0.f, acc1 = 0.f, acc2 = 0.f, acc3 = 0.f;
        for (int k = 0; k < 128; k += 4) {
            float4 x0 = *(const float4*)&xs[n_base     ][k];
            float4 x1 = *(const float4*)&xs[n_base +  8][k];
            float4 x2 = *(const float4*)&xs[n_base + 16][k];
            float4 x3 = *(const float4*)&xs[n_base + 24][k];
            float w0 = W[(k + 0) * wstride + wcol];
            float w1 = W[(k + 1) * wstride + wcol];
            float w2 = W[(k + 2) * wstride + wcol];
            float w3 = W[(k + 3) * wstride + wcol];
            acc0 += x0.x * w0 + x0.y * w1 + x0.z * w2 + x0.w * w3;
            acc1 += x1.x * w0 + x1.y * w1 + x1.z * w2 + x1.w * w3;
            acc2 += x2.x * w0 + x2.y * w1 + x2.z * w2 + x2.w * w3;
            acc3 += x3.x * w0 + x3.y * w1 + x3.z * w2 + x3.w * w3;
        }

        if (cg < 4) {
            int so = c_local * 4 + cg;   // swizzle
            if (ok0) hjb[(size_t)(n0 + n_base     ) * 128 + so] = f2h(acc0);
            if (ok1) hjb[(size_t)(n0 + n_base +  8) * 128 + so] = f2h(acc1);
            if (ok2) hjb[(size_t)(n0 + n_base + 16) * 128 + so] = f2h(acc2);
            if (ok3) hjb[(size_t)(n0 + n_base + 24) * 128 + so] = f2h(acc3);
        } else if (cg < 8) {
            if (ok0) sn16[(size_t)(n0 + n_base     ) * 128 + wcol] = f2h(acc0);
            if (ok1) sn16[(size_t)(n0 + n_base +  8) * 128 + wcol] = f2h(acc1);
            if (ok2) sn16[(size_t)(n0 + n_base + 16) * 128 + wcol] = f2h(acc2);
            if (ok3) sn16[(size_t)(n0 + n_base + 24) * 128 + wcol] = f2h(acc3);
        } else {
            float* outb = (cg == 8) ? self_term : (cg == 9) ? AI : AJ;
            if (ok0) outb[(size_t)(n0 + n_base     ) * 32 + wcol] = acc0;
            if (ok1) outb[(size_t)(n0 + n_base +  8) * 32 + wcol] = acc1;
            if (ok2) outb[(size_t)(n0 + n_base + 16) * 32 + wcol] = acc2;
            if (ok3) outb[(size_t)(n0 + n_base + 24) * 32 + wcol] = acc3;
        }
    }
}

// -------------------------------------------------------------------------
// FUSED edge aggregation + tail. z never leaves LDS.
// Edge walk: counting-sort by (node,r) in LDS, register-accumulated runs,
// 8-deep batched prefetch (8 gathers in flight per half-wave).
// -------------------------------------------------------------------------
__global__ __launch_bounds__(256) void edge_tail(
    const unsigned short* __restrict__ hjb,  // [N*128] fp16 swizzled
    const unsigned short* __restrict__ sn16, // [N*128] fp16
    const float* __restrict__ AJ,        // [N,32]
    const float* __restrict__ AI,        // [N,32]
    const int*   __restrict__ offsets,   // [G+1]
    const int*   __restrict__ sorted,    // [E]
    const float* __restrict__ W_q,       // [R,128,32]
    const float* __restrict__ W_k,
    const float* __restrict__ W_v,
    const float* __restrict__ W_rel,     // [R]
    float* __restrict__ out,             // [N,32]; holds self_term on entry
    int N)
{
    __shared__ float agg[NB_][R_][128];   // 32 KB; z, then q/k/v overlay
    __shared__ float den[NB_][R_][H_];    // 1 KB
    __shared__ float ai [NB_][32];        // 1 KB
    __shared__ int   sortbuf[2 * EMAX_];  // 2.5 KB; ebuf+sbuf, later psi_l
    __shared__ int   bstart[64];
    __shared__ int   bcur[64];
    __shared__ float mskl[NB_ * 8];       // 256 B

    int*   ebuf  = sortbuf;
    int*   sbuf  = sortbuf + EMAX_;
    float* psi_l = (float*)sortbuf;       // overlaid after walk

    const int tid = threadIdx.x;
    const int n0  = blockIdx.x * NB_;
    float* aggp = &agg[0][0][0];

    const int e0 = offsets[blockIdx.x];
    const int e1 = offsets[blockIdx.x + 1];
    const int ecount_raw = e1 - e0;
    const int ecount = (ecount_raw < EMAX_) ? ecount_raw : EMAX_;

    for (int i4 = tid; i4 < NB_ * R_ * 32; i4 += 256)
        ((float4*)aggp)[i4] = make_float4(0.f, 0.f, 0.f, 0.f);
    (&den[0][0][0])[tid] = 0.f;                     // NB*R*H == 256
    {
        int nl = tid >> 5, rh = tid & 31;
        ai[nl][rh] = (n0 + nl < N) ? AI[(size_t)(n0 + nl) * 32 + rh] : 0.f;
    }
    if (tid < 64) bstart[tid] = 0;
    for (int i = tid; i < ecount; i += 256) ebuf[i] = sorted[e0 + i];
    __syncthreads();

    // counting sort by key = nl*8 + r
    for (int i = tid; i < ecount; i += 256) {
        int pk = ebuf[i];
        int key = (((pk >> 20) & 7) << 3) | ((pk >> 17) & 7);
        atomicAdd(&bstart[key], 1);
    }
    __syncthreads();
    if (tid < 64) {
        int v = bstart[tid];
        int s = v;
        #pragma unroll
        for (int d = 1; d < 64; d <<= 1) {
            int t = __shfl_up(s, d, 64);
            if (tid >= d) s += t;
        }
        bstart[tid] = s - v;
        bcur[tid]   = s - v;
    }
    __syncthreads();
    for (int i = tid; i < ecount; i += 256) {
        int pk = ebuf[i];
        int key = (((pk >> 20) & 7) << 3) | ((pk >> 17) & 7);
        int pos = atomicAdd(&bcur[key], 1);
        sbuf[pos] = pk;
    }
    __syncthreads();

    // ---- walk: half-wave = one node, 8-deep batched prefetch ----
    {
        const int nl = tid >> 5;
        const int l  = tid & 31;
        int s_ = bstart[nl * 8];
        int t_ = (nl == 7) ? ecount : bstart[nl * 8 + 8];

        int cur_r = -1;
        float acc0 = 0.f, acc1 = 0.f, acc2 = 0.f, acc3 = 0.f;
        float dn0 = 0.f, dn1 = 0.f, dn2 = 0.f, dn3 = 0.f;

        for (int base = s_; base < t_; base += 8) {
            int     pk[8];
            ushort4 hv[8];
            float4  aj[8];
            #pragma unroll
            for (int b = 0; b < 8; ++b) {
                if (base + b < t_) {
                    pk[b] = sbuf[base + b];
                    int src = pk[b] & 0x1FFFF;
                    int r   = (pk[b] >> 17) & 7;
                    hv[b] = *(const ushort4*)(hjb + (size_t)src * 128 + l * 4);
                    aj[b] = *(const float4*)(AJ + (size_t)src * 32 + r * 4);
                }
            }
            #pragma unroll
            for (int b = 0; b < 8; ++b) {
                if (base + b < t_) {
                    int r = (pk[b] >> 17) & 7;
                    if (r != cur_r) {
                        if (cur_r >= 0) {
                            float* dp = &agg[nl][cur_r][l];
                            atomicAdd(dp,      acc0); atomicAdd(dp + 32, acc1);
                            atomicAdd(dp + 64, acc2); atomicAdd(dp + 96, acc3);
                            if (l < 4) {
                                float dv = (l == 0) ? dn0 : (l == 1) ? dn1 : (l == 2) ? dn2 : dn3;
                                atomicAdd(&den[nl][cur_r][l], dv);
                            }
                        }
                        cur_r = r;
                        acc0 = acc1 = acc2 = acc3 = 0.f;
                        dn0 = dn1 = dn2 = dn3 = 0.f;
                    }
                    const float* aip = &ai[nl][r * 4];
                    float a0 = aip[0] + aj[b].x; a0 = (a0 > 0.f) ? a0 : 0.2f * a0;
                    float a1 = aip[1] + aj[b].y; a1 = (a1 > 0.f) ? a1 : 0.2f * a1;
                    float a2 = aip[2] + aj[b].z; a2 = (a2 > 0.f) ? a2 : 0.2f * a2;
                    float a3 = aip[3] + aj[b].w; a3 = (a3 > 0.f) ? a3 : 0.2f * a3;
                    float x0 = __expf(a0), x1 = __expf(a1), x2 = __expf(a2), x3 = __expf(a3);
                    dn0 += x0; dn1 += x1; dn2 += x2; dn3 += x3;
                    acc0 += x0 * h2f(hv[b].x); acc1 += x1 * h2f(hv[b].y);
                    acc2 += x2 * h2f(hv[b].z); acc3 += x3 * h2f(hv[b].w);
                }
            }
        }
        if (cur_r >= 0) {
            float* dp = &agg[nl][cur_r][l];
            atomicAdd(dp,      acc0); atomicAdd(dp + 32, acc1);
            atomicAdd(dp + 64, acc2); atomicAdd(dp + 96, acc3);
            if (l < 4) {
                float dv = (l == 0) ? dn0 : (l == 1) ? dn1 : (l == 2) ? dn2 : dn3;
                atomicAdd(&den[nl][cur_r][l], dv);
            }
        }
    }
    // overflow fallback (practically never taken)
    if (ecount_raw > EMAX_) {
        const int slot = tid >> 5;
        const int l    = tid & 31;
        for (int k = e0 + EMAX_ + slot; k < e1; k += 8) {
            int pk  = sorted[k];
            int src = pk & 0x1FFFF;
            int r   = (pk >> 17) & 7;
            int nl  = (pk >> 20) & 7;
            ushort4 hv = *(const ushort4*)(hjb + (size_t)src * 128 + l * 4);
            float4  aj = *(const float4*)(AJ + (size_t)src * 32 + r * 4);
            const float* aip = &ai[nl][r * 4];
            float a0 = aip[0] + aj.x; a0 = (a0 > 0.f) ? a0 : 0.2f * a0;
            float a1 = aip[1] + aj.y; a1 = (a1 > 0.f) ? a1 : 0.2f * a1;
            float a2 = aip[2] + aj.z; a2 = (a2 > 0.f) ? a2 : 0.2f * a2;
            float a3 = aip[3] + aj.w; a3 = (a3 > 0.f) ? a3 : 0.2f * a3;
            float x0 = __expf(a0), x1 = __expf(a1), x2 = __expf(a2), x3 = __expf(a3);
            if (l < 4) {
                float myex = (l == 0) ? x0 : (l == 1) ? x1 : (l == 2) ? x2 : x3;
                atomicAdd(&den[nl][r][l], myex);
            }
            float* dp = &agg[nl][r][l];
            atomicAdd(dp,      x0 * h2f(hv.x));
            atomicAdd(dp + 32, x1 * h2f(hv.y));
            atomicAdd(dp + 64, x2 * h2f(hv.z));
            atomicAdd(dp + 96, x3 * h2f(hv.w));
        }
    }
    __syncthreads();

    // ---- z = agg/(den+eps) + self_node (stays in LDS) ----
    for (int i4 = tid; i4 < NB_ * R_ * 32; i4 += 256) {
        int nl  = i4 >> 8;
        int rr  = (i4 >> 5) & 7;
        int hc4 = i4 & 31;
        int h   = hc4 >> 3;
        float invd = 1.f / (den[nl][rr][h] + 1e-16f);
        float4 a4 = ((float4*)aggp)[i4];
        a4.x *= invd; a4.y *= invd; a4.z *= invd; a4.w *= invd;
        if (n0 + nl < N) {
            ushort4 s4 = *(const ushort4*)(sn16 + (size_t)(n0 + nl) * 128 + hc4 * 4);
            a4.x += h2f(s4.x); a4.y += h2f(s4.y); a4.z += h2f(s4.z); a4.w += h2f(s4.w);
        }
        ((float4*)aggp)[i4] = a4;
    }
    __syncthreads();

    // ---- q,k,v: wave w -> relations {w,w+4}; half-waves 4 nodes each ----
    const int w    = tid >> 6;
    const int lane = tid & 63;
    const int c    = lane & 31;
    const int nh   = lane >> 5;
    const int r0   = w, r1 = w + 4;
    const int nbase = nh * 4;

    float qa[2][4], ka[2][4], va[2][4];
    #pragma unroll
    for (int s = 0; s < 2; ++s)
        #pragma unroll
        for (int n = 0; n < 4; ++n) { qa[s][n] = 0.f; ka[s][n] = 0.f; va[s][n] = 0.f; }
    {
        const float* wq0 = W_q + r0 * 4096 + c;
        const float* wk0 = W_k + r0 * 4096 + c;
        const float* wv0 = W_v + r0 * 4096 + c;
        const float* wq1 = W_q + r1 * 4096 + c;
        const float* wk1 = W_k + r1 * 4096 + c;
        const float* wv1 = W_v + r1 * 4096 + c;
        for (int d = 0; d < 128; d += 4) {
            float4 z0[4], z1[4];
            #pragma unroll
            for (int n = 0; n < 4; ++n) {
                z0[n] = *(const float4*)&agg[nbase + n][r0][d];
                z1[n] = *(const float4*)&agg[nbase + n][r1][d];
            }
            #pragma unroll
            for (int j = 0; j < 4; ++j) {
                float a0 = wq0[(d + j) * 32], b0 = wk0[(d + j) * 32], c0 = wv0[(d + j) * 32];
                float a1 = wq1[(d + j) * 32], b1 = wk1[(d + j) * 32], c1 = wv1[(d + j) * 32];
                #pragma unroll
                for (int n = 0; n < 4; ++n) {
                    float z0j = (&z0[n].x)[j], z1j = (&z1[n].x)[j];
                    qa[0][n] += z0j * a0; ka[0][n] += z0j * b0; va[0][n] += z0j * c0;
                    qa[1][n] += z1j * a1; ka[1][n] += z1j * b1; va[1][n] += z1j * c1;
                }
            }
        }
    }
    __syncthreads();   // all z reads done; overlay padded q/k/v onto agg
    float* qs  = aggp;
    float* ks2 = aggp + NB_ * NS_;
    float* vs2 = aggp + 2 * NB_ * NS_;      // 6912 <= 8192
    #pragma unroll
    for (int s = 0; s < 2; ++s) {
        int rr = w + s * 4;
        #pragma unroll
        for (int n = 0; n < 4; ++n) {
            int base = (nbase + n) * NS_ + rr * QS_ + c;
            qs [base] = qa[s][n];
            ks2[base] = ka[s][n];
            vs2[base] = va[s][n];
        }
    }
    __syncthreads();

    // ---- psi[n][rr][ss] (psi_l overlays the sort buffers) ----
    for (int idx = tid; idx < NB_ * 64; idx += 256) {
        int n = idx >> 6, rr = (idx >> 3) & 7, ss = idx & 7;
        const float4* q4 = (const float4*)&qs [n * NS_ + rr * QS_];
        const float4* k4 = (const float4*)&ks2[n * NS_ + ss * QS_];
        float p = 0.f;
        #pragma unroll
        for (int c4 = 0; c4 < 8; ++c4) {
            float4 a = q4[c4], b = k4[c4];
            p += a.x * b.x + a.y * b.y + a.z * b.z + a.w * b.w;
        }
        psi_l[idx] = p;
    }
    __syncthreads();
    if (tid < NB_ * 8) {
        float* row = &psi_l[tid * 8];
        float m = -INFINITY;
        #pragma unroll
        for (int s = 0; s < 8; ++s) m = fmaxf(m, row[s]);
        float sum = 0.f;
        #pragma unroll
        for (int s = 0; s < 8; ++s) { float e = __expf(row[s] - m); row[s] = e; sum += e; }
        float inv = 1.f / sum;
        #pragma unroll
        for (int s = 0; s < 8; ++s) row[s] *= inv;
    }
    __syncthreads();

    // ---- delta ----
    float dl[2][4];
    #pragma unroll
    for (int s = 0; s < 2; ++s)
        #pragma unroll
        for (int n = 0; n < 4; ++n) dl[s][n] = 0.f;
    #pragma unroll
    for (int s = 0; s < 8; ++s) {
        #pragma unroll
        for (int n = 0; n < 4; ++n) {
            float vv = vs2[(nbase + n) * NS_ + s * QS_ + c];
            dl[0][n] += psi_l[(nbase + n) * 64 + r0 * 8 + s] * vv;
            dl[1][n] += psi_l[(nbase + n) * 64 + r1 * 8 + s] * vv;
        }
    }
    __syncthreads();
    #pragma unroll
    for (int s = 0; s < 2; ++s) {
        int rr = w + s * 4;
        #pragma unroll
        for (int n = 0; n < 4; ++n)
            qs[(nbase + n) * NS_ + rr * QS_ + c] = dl[s][n];
    }
    __syncthreads();

    // ---- mask ----
    if (tid < NB_ * 8) {
        int n = tid >> 3, rr = tid & 7;
        float s = 0.f;
        #pragma unroll
        for (int cc = 0; cc < 32; ++cc) s += qs[n * NS_ + rr * QS_ + cc];
        mskl[tid] = (s != 0.f) ? 1.f : 0.f;
    }
    __syncthreads();

    // ---- out ----
    {
        int n = tid >> 5, cc = tid & 31;
        if (n0 + n < N) {
            float st = out[(size_t)(n0 + n) * 32 + cc];
            float o = 0.f;
            #pragma unroll
            for (int rr = 0; rr < 8; ++rr)
                o += (qs[n * NS_ + rr * QS_ + cc] + st * mskl[n * 8 + rr]) * W_rel[rr];
            out[(size_t)(n0 + n) * 32 + cc] = o;
        }
    }
}

// -------------------------------------------------------------------------
extern "C" void kernel_launch(void* const* d_in, const int* in_sizes, int n_in,
                              void* d_out, int out_size, void* d_ws, size_t ws_size,
                              hipStream_t stream)
{
    const float* x      = (const float*)d_in[0];
    const int*   ei     = (const int*)  d_in[1];   // [2,E]
    const int*   et     = (const int*)  d_in[2];   // [E]
    const float* Wj     = (const float*)d_in[3];
    const float* Wi     = (const float*)d_in[4];
    const float* natt   = (const float*)d_in[5];
    const float* W_q    = (const float*)d_in[6];
    const float* W_k    = (const float*)d_in[7];
    const float* W_v    = (const float*)d_in[8];
    const float* W_self = (const float*)d_in[9];
    const float* W_sn   = (const float*)d_in[10];
    const float* W_rel  = (const float*)d_in[11];
    float* out = (float*)d_out;

    const int N = in_sizes[0] / INF_;
    const int E = in_sizes[2];
    const int G = (N + NB_ - 1) / NB_;   // 8-node groups

    // workspace layout (~45 MB)
    float* ws        = (float*)d_ws;
    float* AI        = ws;                               // N*32
    float* AJ        = AI + (size_t)N * 32;              // N*32
    float* M_i       = AJ + (size_t)N * 32;              // 128*32
    float* M_j       = M_i + 128 * 32;                   // 128*32
    unsigned short* hjb  = (unsigned short*)(M_j + 128 * 32);  // N*128 fp16
    unsigned short* sn16 = hjb + (size_t)N * 128;        // N*128 fp16
    int*   counts    = (int*)(sn16 + (size_t)N * 128);   // G+1
    int*   offsets   = counts + (G + 1);                 // G+1
    int*   cursor    = offsets + (G + 1);                // G
    int*   sorted    = cursor + G;                       // E

    // ---- CSR build ----
    hipMemsetAsync(counts, 0, (size_t)(G + 1) * sizeof(int), stream);
    count_edges<<<(E + 255) / 256, 256, 0, stream>>>(ei, counts, E);
    scan_offsets<<<1, 1024, 0, stream>>>(counts, offsets, G);
    hipMemcpyAsync(cursor, offsets, (size_t)G * sizeof(int),
                   hipMemcpyDeviceToDevice, stream);
    scatter_edges<<<(E + 255) / 256, 256, 0, stream>>>(ei, et, cursor, sorted, E);

    // ---- node feature GEMMs (x read once) ----
    prep_M<<<32, 256, 0, stream>>>(Wi, Wj, natt, M_i, M_j);
    fused_gemm<<<(N + 31) / 32, 256, 0, stream>>>(
        x, Wj, W_sn, W_self, M_i, M_j, hjb, sn16, out, AI, AJ, N);

    // ---- fused edge aggregation + tail ----
    edge_tail<<<G, 256, 0, stream>>>(
        hjb, sn16, AJ, AI, offsets, sorted,
        W_q, W_k, W_v, W_rel, out, N);
}

// Round 11
// 731.845 us; speedup vs baseline: 2.2065x; 1.0548x over previous
//
#include <hip/hip_runtime.h>
#include <hip/hip_fp16.h>
#include <math.h>

constexpr int INF_ = 128;  // IN
constexpr int H_   = 4;
constexpr int C_   = 32;
constexpr int R_   = 8;
constexpr int NB_  = 8;    // nodes per block
constexpr int EMAX_ = 512; // staged edges per block (mean 102, sigma ~10; P(>512)~0)

typedef _Float16 half2_t __attribute__((ext_vector_type(2)));

__device__ __forceinline__ unsigned short f2h(float f) {
    return __half_as_ushort(__float2half(f));
}
__device__ __forceinline__ float h2f(unsigned short u) {
    return __half2float(__ushort_as_half(u));
}
__device__ __forceinline__ float dot2(unsigned a, unsigned b, float c) {
#if __has_builtin(__builtin_amdgcn_fdot2)
    return __builtin_amdgcn_fdot2(__builtin_bit_cast(half2_t, a),
                                  __builtin_bit_cast(half2_t, b), c, false);
#else
    c += h2f((unsigned short)(a & 0xFFFF)) * h2f((unsigned short)(b & 0xFFFF));
    c += h2f((unsigned short)(a >> 16))    * h2f((unsigned short)(b >> 16));
    return c;
#endif
}

// -------------------------------------------------------------------------
// CSR build at 8-node GROUP granularity.
// -------------------------------------------------------------------------
__global__ __launch_bounds__(256) void count_edges(
    const int* __restrict__ ei, int* __restrict__ counts, int E)
{
    int e = blockIdx.x * 256 + threadIdx.x;
    if (e >= E) return;
    int dst = ei[E + e];
    atomicAdd(&counts[dst >> 3], 1);
}

__global__ __launch_bounds__(1024) void scan_offsets(
    const int* __restrict__ counts, int* __restrict__ offsets, int G)
{
    __shared__ int wsum[16];
    __shared__ int chunk_tot;
    const int tid  = threadIdx.x;
    const int lane = tid & 63;
    const int wid  = tid >> 6;
    int carry = 0;
    for (int base = 0; base < G; base += 1024) {
        int i = base + tid;
        int v = (i < G) ? counts[i] : 0;
        int s = v;
        #pragma unroll
        for (int d = 1; d < 64; d <<= 1) {
            int t = __shfl_up(s, d, 64);
            if (lane >= d) s += t;
        }
        if (lane == 63) wsum[wid] = s;
        __syncthreads();
        if (tid == 0) {
            int acc = 0;
            #pragma unroll
            for (int w = 0; w < 16; ++w) { int t = wsum[w]; wsum[w] = acc; acc += t; }
            chunk_tot = acc;
        }
        __syncthreads();
        int excl = carry + wsum[wid] + (s - v);
        if (i < G) offsets[i] = excl;
        carry += chunk_tot;
        __syncthreads();
    }
    if (tid == 0) offsets[G] = carry;
}

// packed: src | r<<17 | (dst&7)<<20
__global__ __launch_bounds__(256) void scatter_edges(
    const int* __restrict__ ei, const int* __restrict__ et,
    int* __restrict__ cursor, int* __restrict__ sorted, int E)
{
    int e = blockIdx.x * 256 + threadIdx.x;
    if (e >= E) return;
    int src = ei[e];
    int dst = ei[E + e];
    int r   = et[e];
    int pos = atomicAdd(&cursor[dst >> 3], 1);
    sorted[pos] = src | (r << 17) | ((dst & 7) << 20);
}

// -------------------------------------------------------------------------
// M_i[d][r*4+h] = sum_c Wi[d][h*32+c] * natt[r*4+h][c]
// M_j[d][r*4+h] = sum_c Wj[d][h*32+c] * natt[r*4+h][32+c]
// -------------------------------------------------------------------------
__global__ __launch_bounds__(256) void prep_M(
    const float* __restrict__ Wi, const float* __restrict__ Wj,
    const float* __restrict__ natt,
    float* __restrict__ M_i, float* __restrict__ M_j)
{
    int idx = blockIdx.x * 256 + threadIdx.x;   // 0..8191
    int which = idx >> 12;
    int d  = (idx >> 5) & 127;
    int rh = idx & 31;
    int h  = rh & 3;
    const float* W   = which ? Wj : Wi;
    const float* att = natt + rh * 64 + (which ? 32 : 0);
    float acc = 0.f;
    #pragma unroll
    for (int c = 0; c < 32; ++c)
        acc += W[d * 128 + h * 32 + c] * att[c];
    (which ? M_j : M_i)[d * 32 + rh] = acc;
}

// -------------------------------------------------------------------------
// prep_W: fp16 weight transpose into swizzled-k order matching zh layout.
//   Wt[mat][r][c][m] = W_mat[r][k(m)][c],  k(m) = (m&3)*32 + (m>>2)
// 3*8*32*128 = 98304 elements.
// -------------------------------------------------------------------------
__global__ __launch_bounds__(256) void prep_W(
    const float* __restrict__ W_q, const float* __restrict__ W_k,
    const float* __restrict__ W_v, unsigned short* __restrict__ Wt)
{
    int idx = blockIdx.x * 256 + threadIdx.x;
    if (idx >= 3 * 8 * 32 * 128) return;
    int mat = idx >> 15;            // 0..2
    int rem = idx & 32767;
    int r   = rem >> 12;            // 0..7
    int c   = (rem >> 7) & 31;      // 0..31
    int m   = rem & 127;            // 0..127
    int k   = (m & 3) * 32 + (m >> 2);
    const float* W = (mat == 0) ? W_q : (mat == 1) ? W_k : W_v;
    Wt[idx] = f2h(W[r * 4096 + k * 32 + c]);
}

// -------------------------------------------------------------------------
// Fused node GEMMs — x tile read ONCE per block, all 11 col-groups inside.
// h_j AND self_node emitted fp16 SWIZZLED: buf[node*128 + (col%32)*4 + col/32]
// -------------------------------------------------------------------------
__global__ __launch_bounds__(256) void fused_gemm(
    const float* __restrict__ x,
    const float* __restrict__ Wj,
    const float* __restrict__ Wsn,
    const float* __restrict__ Wself,
    const float* __restrict__ M_i,
    const float* __restrict__ M_j,
    unsigned short* __restrict__ hjb,   // [N*128] fp16 swizzled
    unsigned short* __restrict__ sn16,  // [N*128] fp16 swizzled
    float* __restrict__ self_term,      // = d_out
    float* __restrict__ AI,
    float* __restrict__ AJ,
    int N)
{
    __shared__ float xs[32][128];
    const int n0  = blockIdx.x * 32;
    const int tid = threadIdx.x;

    #pragma unroll
    for (int j = 0; j < 4; ++j) {
        int f4   = tid + 256 * j;
        int row  = f4 >> 5;
        int col4 = f4 & 31;
        float4 v = make_float4(0.f, 0.f, 0.f, 0.f);
        if (n0 + row < N)
            v = *(const float4*)(x + (size_t)(n0 + row) * 128 + col4 * 4);
        *(float4*)(&xs[row][col4 * 4]) = v;
    }
    __syncthreads();

    const int c_local = tid & 31;
    const int n_base  = tid >> 5;
    const bool ok0 = (n0 + n_base      < N);
    const bool ok1 = (n0 + n_base +  8 < N);
    const bool ok2 = (n0 + n_base + 16 < N);
    const bool ok3 = (n0 + n_base + 24 < N);

    for (int cg = 0; cg < 11; ++cg) {
        const int col = cg * 32 + c_local;
        const float* W; int wcol, wstride;
        if (col < 128)      { W = Wj;    wcol = col;       wstride = 128; }
        else if (col < 256) { W = Wsn;   wcol = col - 128; wstride = 128; }
        else if (col < 288) { W = Wself; wcol = col - 256; wstride = 32;  }
        else if (col < 320) { W = M_i;   wcol = col - 288; wstride = 32;  }
        else                { W = M_j;   wcol = col - 320; wstride = 32;  }

        float acc0 = 0.f, acc1 = 0.f, acc2 = 0.f, acc3 = 0.f;
        for (int k = 0; k < 128; k += 4) {
            float4 x0 = *(const float4*)&xs[n_base     ][k];
            float4 x1 = *(const float4*)&xs[n_base +  8][k];
            float4 x2 = *(const float4*)&xs[n_base + 16][k];
            float4 x3 = *(const float4*)&xs[n_base + 24][k];
            float w0 = W[(k + 0) * wstride + wcol];
            float w1 = W[(k + 1) * wstride + wcol];
            float w2 = W[(k + 2) * wstride + wcol];
            float w3 = W[(k + 3) * wstride + wcol];
            acc0 += x0.x * w0 + x0.y * w1 + x0.z * w2 + x0.w * w3;
            acc1 += x1.x * w0 + x1.y * w1 + x1.z * w2 + x1.w * w3;
            acc2 += x2.x * w0 + x2.y * w1 + x2.z * w2 + x2.w * w3;
            acc3 += x3.x * w0 + x3.y * w1 + x3.z * w2 + x3.w * w3;
        }

        if (cg < 4) {
            int so = c_local * 4 + cg;
            if (ok0) hjb[(size_t)(n0 + n_base     ) * 128 + so] = f2h(acc0);
            if (ok1) hjb[(size_t)(n0 + n_base +  8) * 128 + so] = f2h(acc1);
            if (ok2) hjb[(size_t)(n0 + n_base + 16) * 128 + so] = f2h(acc2);
            if (ok3) hjb[(size_t)(n0 + n_base + 24) * 128 + so] = f2h(acc3);
        } else if (cg < 8) {
            int so = c_local * 4 + (cg - 4);
            if (ok0) sn16[(size_t)(n0 + n_base     ) * 128 + so] = f2h(acc0);
            if (ok1) sn16[(size_t)(n0 + n_base +  8) * 128 + so] = f2h(acc1);
            if (ok2) sn16[(size_t)(n0 + n_base + 16) * 128 + so] = f2h(acc2);
            if (ok3) sn16[(size_t)(n0 + n_base + 24) * 128 + so] = f2h(acc3);
        } else {
            float* outb = (cg == 8) ? self_term : (cg == 9) ? AI : AJ;
            if (ok0) outb[(size_t)(n0 + n_base     ) * 32 + wcol] = acc0;
            if (ok1) outb[(size_t)(n0 + n_base +  8) * 32 + wcol] = acc1;
            if (ok2) outb[(size_t)(n0 + n_base + 16) * 32 + wcol] = acc2;
            if (ok3) outb[(size_t)(n0 + n_base + 24) * 32 + wcol] = acc3;
        }
    }
}

// -------------------------------------------------------------------------
// FUSED edge aggregation + tail, register-finalized z, fp16 dot2 tail.
// LDS ~31.75 KB -> 5 blocks/CU.
// -------------------------------------------------------------------------
__global__ __launch_bounds__(256) void edge_tail(
    const unsigned short* __restrict__ hjb,  // [N*128] fp16 swizzled
    const unsigned short* __restrict__ sn16, // [N*128] fp16 swizzled
    const float* __restrict__ AJ,        // [N,32]
    const float* __restrict__ AI,        // [N,32]
    const int*   __restrict__ offsets,   // [G+1]
    const int*   __restrict__ sorted,    // [E]
    const unsigned short* __restrict__ Wt,  // [3][8][32][128] fp16 swizzled-k
    const float* __restrict__ W_rel,     // [R]
    float* __restrict__ out,             // [N,32]; holds self_term on entry
    int N)
{
    __shared__ unsigned int zh[NB_ * R_ * 64];   // 16 KB  z fp16 [n][r][m]/2
    __shared__ unsigned int qkvb[3 * 1024];      // 12 KB  q/k/v fp16; sortbuf overlay
    __shared__ float psi_l[NB_ * 64];            // 2 KB
    __shared__ float ai[NB_][32];                // 1 KB
    __shared__ int   bstart[64];
    __shared__ int   bcur[64];
    __shared__ float mskl[NB_ * 8];              // 256 B

    int* ebuf = (int*)qkvb;            // walk-phase overlay
    int* sbuf = ebuf + EMAX_;

    const int tid = threadIdx.x;
    const int n0  = blockIdx.x * NB_;

    const int e0 = offsets[blockIdx.x];
    const int e1 = offsets[blockIdx.x + 1];
    const int ecount_raw = e1 - e0;
    const int ecount = (ecount_raw < EMAX_) ? ecount_raw : EMAX_;

    // init zh = self_node (fp16 swizzled), load AI, stage edges
    {
        const unsigned int* sn_u = (const unsigned int*)sn16;
        for (int u = tid; u < NB_ * R_ * 64; u += 256) {
            int n  = u >> 9;
            int mu = u & 63;
            zh[u] = (n0 + n < N) ? sn_u[(size_t)(n0 + n) * 64 + mu] : 0u;
        }
        int nl = tid >> 5, rh = tid & 31;
        ai[nl][rh] = (n0 + nl < N) ? AI[(size_t)(n0 + nl) * 32 + rh] : 0.f;
        if (tid < 64) bstart[tid] = 0;
        for (int i = tid; i < ecount; i += 256) ebuf[i] = sorted[e0 + i];
    }
    __syncthreads();

    // counting sort by key = nl*8 + r
    for (int i = tid; i < ecount; i += 256) {
        int pk = ebuf[i];
        int key = (((pk >> 20) & 7) << 3) | ((pk >> 17) & 7);
        atomicAdd(&bstart[key], 1);
    }
    __syncthreads();
    if (tid < 64) {
        int v = bstart[tid];
        int s = v;
        #pragma unroll
        for (int d = 1; d < 64; d <<= 1) {
            int t = __shfl_up(s, d, 64);
            if (tid >= d) s += t;
        }
        bstart[tid] = s - v;
        bcur[tid]   = s - v;
    }
    __syncthreads();
    for (int i = tid; i < ecount; i += 256) {
        int pk = ebuf[i];
        int key = (((pk >> 20) & 7) << 3) | ((pk >> 17) & 7);
        int pos = atomicAdd(&bcur[key], 1);
        sbuf[pos] = pk;
    }
    __syncthreads();

    // ---- walk: half-wave = one node; register-accumulated runs,
    //      finalize z = acc/den + sn in-register, single fp16 store per run.
    {
        const int nl = tid >> 5;
        const int l  = tid & 31;
        int s_ = bstart[nl * 8];
        int t_ = (nl == 7) ? ecount : bstart[nl * 8 + 8];

        ushort4 snv = make_ushort4(0, 0, 0, 0);
        if (n0 + nl < N)
            snv = *(const ushort4*)(sn16 + (size_t)(n0 + nl) * 128 + l * 4);
        float sn0 = h2f(snv.x), sn1 = h2f(snv.y), sn2 = h2f(snv.z), sn3 = h2f(snv.w);

        int cur_r = -1;
        float acc0 = 0.f, acc1 = 0.f, acc2 = 0.f, acc3 = 0.f;
        float dn0 = 0.f, dn1 = 0.f, dn2 = 0.f, dn3 = 0.f;

        for (int base = s_; base < t_; base += 8) {
            int     pk[8];
            ushort4 hv[8];
            float4  aj[8];
            #pragma unroll
            for (int b = 0; b < 8; ++b) {
                if (base + b < t_) {
                    pk[b] = sbuf[base + b];
                    int src = pk[b] & 0x1FFFF;
                    int r   = (pk[b] >> 17) & 7;
                    hv[b] = *(const ushort4*)(hjb + (size_t)src * 128 + l * 4);
                    aj[b] = *(const float4*)(AJ + (size_t)src * 32 + r * 4);
                }
            }
            #pragma unroll
            for (int b = 0; b < 8; ++b) {
                if (base + b < t_) {
                    int r = (pk[b] >> 17) & 7;
                    if (r != cur_r) {
                        if (cur_r >= 0) {
                            float i0 = 1.f / (dn0 + 1e-16f), i1 = 1.f / (dn1 + 1e-16f);
                            float i2 = 1.f / (dn2 + 1e-16f), i3 = 1.f / (dn3 + 1e-16f);
                            unsigned lo = (unsigned)f2h(acc0 * i0 + sn0) |
                                          ((unsigned)f2h(acc1 * i1 + sn1) << 16);
                            unsigned hi = (unsigned)f2h(acc2 * i2 + sn2) |
                                          ((unsigned)f2h(acc3 * i3 + sn3) << 16);
                            unsigned int* zp = &zh[((nl * 8 + cur_r) << 6) + l * 2];
                            zp[0] = lo; zp[1] = hi;
                        }
                        cur_r = r;
                        acc0 = acc1 = acc2 = acc3 = 0.f;
                        dn0 = dn1 = dn2 = dn3 = 0.f;
                    }
                    const float* aip = &ai[nl][r * 4];
                    float a0 = aip[0] + aj[b].x; a0 = (a0 > 0.f) ? a0 : 0.2f * a0;
                    float a1 = aip[1] + aj[b].y; a1 = (a1 > 0.f) ? a1 : 0.2f * a1;
                    float a2 = aip[2] + aj[b].z; a2 = (a2 > 0.f) ? a2 : 0.2f * a2;
                    float a3 = aip[3] + aj[b].w; a3 = (a3 > 0.f) ? a3 : 0.2f * a3;
                    float x0 = __expf(a0), x1 = __expf(a1), x2 = __expf(a2), x3 = __expf(a3);
                    dn0 += x0; dn1 += x1; dn2 += x2; dn3 += x3;
                    acc0 += x0 * h2f(hv[b].x); acc1 += x1 * h2f(hv[b].y);
                    acc2 += x2 * h2f(hv[b].z); acc3 += x3 * h2f(hv[b].w);
                }
            }
        }
        if (cur_r >= 0) {
            float i0 = 1.f / (dn0 + 1e-16f), i1 = 1.f / (dn1 + 1e-16f);
            float i2 = 1.f / (dn2 + 1e-16f), i3 = 1.f / (dn3 + 1e-16f);
            unsigned lo = (unsigned)f2h(acc0 * i0 + sn0) |
                          ((unsigned)f2h(acc1 * i1 + sn1) << 16);
            unsigned hi = (unsigned)f2h(acc2 * i2 + sn2) |
                          ((unsigned)f2h(acc3 * i3 + sn3) << 16);
            unsigned int* zp = &zh[((nl * 8 + cur_r) << 6) + l * 2];
            zp[0] = lo; zp[1] = hi;
        }
    }
    __syncthreads();

    // ---- q,k,v via fp16 dot2: wave w -> relations {w,w+4}; half-waves 4 nodes
    const int w    = tid >> 6;
    const int lane = tid & 63;
    const int c    = lane & 31;
    const int nh   = lane >> 5;
    const int r0   = w, r1 = w + 4;
    const int nbase = nh * 4;

    float qa[2][4], ka[2][4], va[2][4];
    #pragma unroll
    for (int s = 0; s < 2; ++s)
        #pragma unroll
        for (int n = 0; n < 4; ++n) { qa[s][n] = 0.f; ka[s][n] = 0.f; va[s][n] = 0.f; }
    {
        const unsigned int* wtu = (const unsigned int*)Wt;
        const unsigned int* wq0 = wtu +                 ((r0 * 32 + c) << 6);
        const unsigned int* wk0 = wtu + (8 * 32 * 64) + ((r0 * 32 + c) << 6);
        const unsigned int* wv0 = wtu + (16 * 32 * 64) + ((r0 * 32 + c) << 6);
        const unsigned int* wq1 = wtu +                 ((r1 * 32 + c) << 6);
        const unsigned int* wk1 = wtu + (8 * 32 * 64) + ((r1 * 32 + c) << 6);
        const unsigned int* wv1 = wtu + (16 * 32 * 64) + ((r1 * 32 + c) << 6);
        for (int mc = 0; mc < 64; mc += 4) {
            uint4 q0 = *(const uint4*)(wq0 + mc);
            uint4 k0 = *(const uint4*)(wk0 + mc);
            uint4 v0 = *(const uint4*)(wv0 + mc);
            uint4 q1 = *(const uint4*)(wq1 + mc);
            uint4 k1 = *(const uint4*)(wk1 + mc);
            uint4 v1 = *(const uint4*)(wv1 + mc);
            #pragma unroll
            for (int n = 0; n < 4; ++n) {
                uint4 z0 = *(const uint4*)&zh[(((nbase + n) * 8 + r0) << 6) + mc];
                uint4 z1 = *(const uint4*)&zh[(((nbase + n) * 8 + r1) << 6) + mc];
                float a;
                a = qa[0][n]; a = dot2(z0.x, q0.x, a); a = dot2(z0.y, q0.y, a);
                a = dot2(z0.z, q0.z, a); a = dot2(z0.w, q0.w, a); qa[0][n] = a;
                a = ka[0][n]; a = dot2(z0.x, k0.x, a); a = dot2(z0.y, k0.y, a);
                a = dot2(z0.z, k0.z, a); a = dot2(z0.w, k0.w, a); ka[0][n] = a;
                a = va[0][n]; a = dot2(z0.x, v0.x, a); a = dot2(z0.y, v0.y, a);
                a = dot2(z0.z, v0.z, a); a = dot2(z0.w, v0.w, a); va[0][n] = a;
                a = qa[1][n]; a = dot2(z1.x, q1.x, a); a = dot2(z1.y, q1.y, a);
                a = dot2(z1.z, q1.z, a); a = dot2(z1.w, q1.w, a); qa[1][n] = a;
                a = ka[1][n]; a = dot2(z1.x, k1.x, a); a = dot2(z1.y, k1.y, a);
                a = dot2(z1.z, k1.z, a); a = dot2(z1.w, k1.w, a); ka[1][n] = a;
                a = va[1][n]; a = dot2(z1.x, v1.x, a); a = dot2(z1.y, v1.y, a);
                a = dot2(z1.z, v1.z, a); a = dot2(z1.w, v1.w, a); va[1][n] = a;
            }
        }
    }
    __syncthreads();   // sortbuf no longer needed; store q/k/v fp16
    unsigned short* qh = (unsigned short*)qkvb;          // [n][r][32] fp16
    unsigned short* kh = qh + 2048;
    unsigned short* vh = qh + 4096;
    #pragma unroll
    for (int s = 0; s < 2; ++s) {
        int rr = w + s * 4;
        #pragma unroll
        for (int n = 0; n < 4; ++n) {
            int base = ((nbase + n) * 8 + rr) * 32 + c;
            qh[base] = f2h(qa[s][n]);
            kh[base] = f2h(ka[s][n]);
            vh[base] = f2h(va[s][n]);
        }
    }
    __syncthreads();

    // ---- psi[n][rr][ss] = <q[n,rr], k[n,ss]> (fp16 dot2) ----
    for (int idx = tid; idx < NB_ * 64; idx += 256) {
        int n = idx >> 6, rr = (idx >> 3) & 7, ss = idx & 7;
        const unsigned int* q4 = (const unsigned int*)(qh + (n * 8 + rr) * 32);
        const unsigned int* k4 = (const unsigned int*)(kh + (n * 8 + ss) * 32);
        float p = 0.f;
        #pragma unroll
        for (int c2 = 0; c2 < 16; c2 += 4) {
            uint4 a = *(const uint4*)(q4 + c2);
            uint4 b = *(const uint4*)(k4 + c2);
            p = dot2(a.x, b.x, p); p = dot2(a.y, b.y, p);
            p = dot2(a.z, b.z, p); p = dot2(a.w, b.w, p);
        }
        psi_l[idx] = p;
    }
    __syncthreads();
    if (tid < NB_ * 8) {
        float* row = &psi_l[tid * 8];
        float m = -INFINITY;
        #pragma unroll
        for (int s = 0; s < 8; ++s) m = fmaxf(m, row[s]);
        float sum = 0.f;
        #pragma unroll
        for (int s = 0; s < 8; ++s) { float e = __expf(row[s] - m); row[s] = e; sum += e; }
        float inv = 1.f / sum;
        #pragma unroll
        for (int s = 0; s < 8; ++s) row[s] *= inv;
    }
    __syncthreads();

    // ---- delta[n][r][c] = sum_s psi * v; store fp32 over q/k region ----
    float dl[2][4];
    #pragma unroll
    for (int s = 0; s < 2; ++s)
        #pragma unroll
        for (int n = 0; n < 4; ++n) dl[s][n] = 0.f;
    #pragma unroll
    for (int s = 0; s < 8; ++s) {
        #pragma unroll
        for (int n = 0; n < 4; ++n) {
            float vv = h2f(vh[((nbase + n) * 8 + s) * 32 + c]);
            dl[0][n] += psi_l[(nbase + n) * 64 + r0 * 8 + s] * vv;
            dl[1][n] += psi_l[(nbase + n) * 64 + r1 * 8 + s] * vv;
        }
    }
    __syncthreads();   // q/k reads (psi) complete; overlay delta fp32
    float* dbuf = (float*)qkvb;        // [n][r][32] fp32 = 8 KB (q+k region)
    #pragma unroll
    for (int s = 0; s < 2; ++s) {
        int rr = w + s * 4;
        #pragma unroll
        for (int n = 0; n < 4; ++n)
            dbuf[((nbase + n) * 8 + rr) * 32 + c] = dl[s][n];
    }
    __syncthreads();

    // ---- mask[n][r] = (sum_c delta != 0) ----
    if (tid < NB_ * 8) {
        int n = tid >> 3, rr = tid & 7;
        float s = 0.f;
        #pragma unroll
        for (int cc = 0; cc < 32; ++cc) s += dbuf[(n * 8 + rr) * 32 + cc];
        mskl[tid] = (s != 0.f) ? 1.f : 0.f;
    }
    __syncthreads();

    // ---- out[n] = sum_r (delta + self_term*mask) * W_rel[r] ----
    {
        int n = tid >> 5, cc = tid & 31;
        if (n0 + n < N) {
            float st = out[(size_t)(n0 + n) * 32 + cc];
            float o = 0.f;
            #pragma unroll
            for (int rr = 0; rr < 8; ++rr)
                o += (dbuf[(n * 8 + rr) * 32 + cc] + st * mskl[n * 8 + rr]) * W_rel[rr];
            out[(size_t)(n0 + n) * 32 + cc] = o;
        }
    }
}

// -------------------------------------------------------------------------
extern "C" void kernel_launch(void* const* d_in, const int* in_sizes, int n_in,
                              void* d_out, int out_size, void* d_ws, size_t ws_size,
                              hipStream_t stream)
{
    const float* x      = (const float*)d_in[0];
    const int*   ei     = (const int*)  d_in[1];   // [2,E]
    const int*   et     = (const int*)  d_in[2];   // [E]
    const float* Wj     = (const float*)d_in[3];
    const float* Wi     = (const float*)d_in[4];
    const float* natt   = (const float*)d_in[5];
    const float* W_q    = (const float*)d_in[6];
    const float* W_k    = (const float*)d_in[7];
    const float* W_v    = (const float*)d_in[8];
    const float* W_self = (const float*)d_in[9];
    const float* W_sn   = (const float*)d_in[10];
    const float* W_rel  = (const float*)d_in[11];
    float* out = (float*)d_out;

    const int N = in_sizes[0] / INF_;
    const int E = in_sizes[2];
    const int G = (N + NB_ - 1) / NB_;   // 8-node groups

    // workspace layout (~42 MB)
    float* ws        = (float*)d_ws;
    float* AI        = ws;                               // N*32
    float* AJ        = AI + (size_t)N * 32;              // N*32
    float* M_i       = AJ + (size_t)N * 32;              // 128*32
    float* M_j       = M_i + 128 * 32;                   // 128*32
    unsigned short* hjb  = (unsigned short*)(M_j + 128 * 32);  // N*128 fp16
    unsigned short* sn16 = hjb + (size_t)N * 128;        // N*128 fp16
    unsigned short* Wt   = sn16 + (size_t)N * 128;       // 3*8*32*128 fp16
    int*   counts    = (int*)(Wt + 3 * 8 * 32 * 128);    // G+1
    int*   offsets   = counts + (G + 1);                 // G+1
    int*   cursor    = offsets + (G + 1);                // G
    int*   sorted    = cursor + G;                       // E

    // ---- CSR build ----
    hipMemsetAsync(counts, 0, (size_t)(G + 1) * sizeof(int), stream);
    count_edges<<<(E + 255) / 256, 256, 0, stream>>>(ei, counts, E);
    scan_offsets<<<1, 1024, 0, stream>>>(counts, offsets, G);
    hipMemcpyAsync(cursor, offsets, (size_t)G * sizeof(int),
                   hipMemcpyDeviceToDevice, stream);
    scatter_edges<<<(E + 255) / 256, 256, 0, stream>>>(ei, et, cursor, sorted, E);

    // ---- weight/feature prep ----
    prep_M<<<32, 256, 0, stream>>>(Wi, Wj, natt, M_i, M_j);
    prep_W<<<(3 * 8 * 32 * 128 + 255) / 256, 256, 0, stream>>>(W_q, W_k, W_v, Wt);
    fused_gemm<<<(N + 31) / 32, 256, 0, stream>>>(
        x, Wj, W_sn, W_self, M_i, M_j, hjb, sn16, out, AI, AJ, N);

    // ---- fused edge aggregation + tail ----
    edge_tail<<<G, 256, 0, stream>>>(
        hjb, sn16, AJ, AI, offsets, sorted, Wt, W_rel, out, N);
}